// Round 1
// baseline (25435.753 us; speedup 1.0000x reference)
//
#include <hip/hip_runtime.h>
#include <cstdint>
#include <cstddef>

#define T_LEN 2048
#define B_SZ 4
#define C_CH 512
#define H_N 8
#define DK_ 64
#define FC_CH 2048
#define L_N 6
#define KW 3
#define S_CH 256

constexpr int BM = 128, BT = 128, BKC = 16;

// Generic "conv1d as GEMM": out[b,m,t] = act( sum_{c,k} W[m,c,k] * in[b,c,t+k-pl] + bias[m] [+ res] ) [* mask]
// KK = taps (1 or 3). Input staged as KK shifted copies so inner reads are aligned float4.
template<int KK>
__global__ __launch_bounds__(256)
void conv_gemm(const float* __restrict__ in, const float* __restrict__ W,
               const float* __restrict__ bias, const float* __restrict__ res,
               const float* __restrict__ mask, float* __restrict__ out,
               int M, int Cin, int pl, int do_relu, int mask_in, int mask_out)
{
    constexpr int CKW = BKC * KK;      // 16 or 48
    constexpr int WST = CKW + 2;       // padded weight row stride (2-way conflicts = free)
    __shared__ float sIn[CKW * BT];
    __shared__ float sW[BM * WST];
    const int tid = threadIdx.x;
    const int tx = tid & 15, ty = tid >> 4;
    const int t0 = blockIdx.x * BT;
    const int m0 = blockIdx.y * BM;
    const int b = blockIdx.z;
    const float* inb = in + (size_t)b * Cin * T_LEN;
    const float* mk = mask + (size_t)b * T_LEN;

    float acc[8][8];
#pragma unroll
    for (int i = 0; i < 8; ++i)
#pragma unroll
        for (int j = 0; j < 8; ++j) acc[i][j] = 0.f;

    for (int c0 = 0; c0 < Cin; c0 += BKC) {
        // stage input: KK shifted copies, row ck = c*KK+k holds in[c0+c][t0 + tt + k - pl]
        for (int id = tid; id < CKW * BT; id += 256) {
            int tt = id & (BT - 1);
            int ck = id >> 7;          // BT == 128
            int c = ck / KK;
            int k = ck - c * KK;
            int gt = t0 + tt + k - pl;
            float v = 0.f;
            if (gt >= 0 && gt < T_LEN) {
                v = inb[(size_t)(c0 + c) * T_LEN + gt];
                if (mask_in) v *= mk[gt];
            }
            sIn[ck * BT + tt] = v;
        }
        // stage weights row-major [m][ck] (global-coalesced along ck)
        for (int id = tid; id < BM * CKW; id += 256) {
            int ck = id % CKW;
            int m = id / CKW;
            sW[m * WST + ck] = W[(size_t)(m0 + m) * (Cin * KK) + (size_t)c0 * KK + ck];
        }
        __syncthreads();
#pragma unroll 4
        for (int ck = 0; ck < CKW; ++ck) {
            const float4 i0 = *reinterpret_cast<const float4*>(&sIn[ck * BT + tx * 8]);
            const float4 i1 = *reinterpret_cast<const float4*>(&sIn[ck * BT + tx * 8 + 4]);
            float iv[8] = {i0.x, i0.y, i0.z, i0.w, i1.x, i1.y, i1.z, i1.w};
            float wv[8];
#pragma unroll
            for (int i = 0; i < 8; ++i) wv[i] = sW[(ty * 8 + i) * WST + ck];
#pragma unroll
            for (int i = 0; i < 8; ++i)
#pragma unroll
                for (int j = 0; j < 8; ++j)
                    acc[i][j] += wv[i] * iv[j];
        }
        __syncthreads();
    }
    // epilogue
#pragma unroll
    for (int i = 0; i < 8; ++i) {
        int m = m0 + ty * 8 + i;
        float bv = bias[m];
        size_t obase = ((size_t)b * M + m) * T_LEN + t0 + tx * 8;
        float v8[8];
#pragma unroll
        for (int j = 0; j < 8; ++j) {
            float v = acc[i][j] + bv;
            if (res) v += res[obase + j];
            if (do_relu) v = fmaxf(v, 0.f);
            if (mask_out) v *= mk[t0 + tx * 8 + j];
            v8[j] = v;
        }
        *reinterpret_cast<float4*>(&out[obase]) = make_float4(v8[0], v8[1], v8[2], v8[3]);
        *reinterpret_cast<float4*>(&out[obase + 4]) = make_float4(v8[4], v8[5], v8[6], v8[7]);
    }
}

// t0[b,c,t] += bias[c] + sum_k f0w[c,k] * nf0[b, t+k-1]
__global__ __launch_bounds__(256)
void f0_add_kernel(const float* __restrict__ nf0, const float* __restrict__ w,
                   const float* __restrict__ bias, float* __restrict__ t0buf)
{
    int t = blockIdx.x * 256 + threadIdx.x;
    int c = blockIdx.y;
    int b = blockIdx.z;
    float acc = bias[c];
#pragma unroll
    for (int k = 0; k < 3; ++k) {
        int gt = t + k - 1;
        if (gt >= 0 && gt < T_LEN) acc += w[c * 3 + k] * nf0[b * T_LEN + gt];
    }
    t0buf[((size_t)b * C_CH + c) * T_LEN + t] += acc;
}

// Flash-style causal attention, fp32. 64 queries per block, one (b,h) per block.
// q/k/v/o layout: [b, h*64+d, t]. Scores masked to -1e4 (matches ref; underflows to 0 in softmax).
__global__ __launch_bounds__(256)
void flash_attn_kernel(const float* __restrict__ q, const float* __restrict__ k,
                       const float* __restrict__ v, float* __restrict__ o)
{
    constexpr int ST = 68;
    __shared__ float sQ[64 * ST];    // [d][qi]
    __shared__ float sKP[64 * ST];   // K tile [d][kj], reused as P tile [kj][qi]
    __shared__ float sVt[64 * ST];   // V transposed [kj][d]
    const int tid = threadIdx.x;
    const int tx = tid & 15, ty = tid >> 4;
    const int qt0 = blockIdx.x * 64;
    const int h = blockIdx.y, b = blockIdx.z;
    const size_t base = ((size_t)b * C_CH + h * DK_) * T_LEN;

    for (int id = tid; id < 64 * 64; id += 256) {
        int d = id >> 6, qi = id & 63;
        sQ[d * ST + qi] = q[base + (size_t)d * T_LEN + qt0 + qi];
    }

    float mrow[4], lrow[4], acc[4][4];
#pragma unroll
    for (int i = 0; i < 4; ++i) {
        mrow[i] = -__builtin_inff();
        lrow[i] = 0.f;
#pragma unroll
        for (int j = 0; j < 4; ++j) acc[i][j] = 0.f;
    }

    for (int kt0 = 0; kt0 <= qt0; kt0 += 64) {
        __syncthreads();   // protect sKP/sVt from previous iteration's reads
        for (int id = tid; id < 64 * 64; id += 256) {
            int d = id >> 6, kj = id & 63;
            sKP[d * ST + kj] = k[base + (size_t)d * T_LEN + kt0 + kj];
        }
#pragma unroll
        for (int r = 0; r < 4; ++r) {
            int dd = r * 16 + ty;
            float4 vv = *reinterpret_cast<const float4*>(&v[base + (size_t)dd * T_LEN + kt0 + tx * 4]);
            sVt[(tx * 4 + 0) * ST + dd] = vv.x;
            sVt[(tx * 4 + 1) * ST + dd] = vv.y;
            sVt[(tx * 4 + 2) * ST + dd] = vv.z;
            sVt[(tx * 4 + 3) * ST + dd] = vv.w;
        }
        __syncthreads();
        // S = Q.K^T  (thread owns qi = ty*4+i, kj = tx*4+j)
        float s[4][4];
#pragma unroll
        for (int i = 0; i < 4; ++i)
#pragma unroll
            for (int j = 0; j < 4; ++j) s[i][j] = 0.f;
#pragma unroll 8
        for (int d = 0; d < 64; ++d) {
            float4 qv = *reinterpret_cast<const float4*>(&sQ[d * ST + ty * 4]);
            float4 kv = *reinterpret_cast<const float4*>(&sKP[d * ST + tx * 4]);
            float qa[4] = {qv.x, qv.y, qv.z, qv.w};
            float ka[4] = {kv.x, kv.y, kv.z, kv.w};
#pragma unroll
            for (int i = 0; i < 4; ++i)
#pragma unroll
                for (int j = 0; j < 4; ++j) s[i][j] += qa[i] * ka[j];
        }
        // scale + causal mask + online softmax
        float p[4][4], mt[4], rs[4];
#pragma unroll
        for (int i = 0; i < 4; ++i) {
            int gq = qt0 + ty * 4 + i;
            mt[i] = -__builtin_inff();
#pragma unroll
            for (int j = 0; j < 4; ++j) {
                int gk = kt0 + tx * 4 + j;
                float sv = s[i][j] * 0.125f;
                if (gk > gq) sv = -1e4f;
                s[i][j] = sv;
                mt[i] = fmaxf(mt[i], sv);
            }
        }
#pragma unroll
        for (int off = 1; off < 16; off <<= 1)
#pragma unroll
            for (int i = 0; i < 4; ++i)
                mt[i] = fmaxf(mt[i], __shfl_xor(mt[i], off));
#pragma unroll
        for (int i = 0; i < 4; ++i) {
            float mnew = fmaxf(mrow[i], mt[i]);
            float alpha = __expf(mrow[i] - mnew);
            mrow[i] = mnew;
            float rsum = 0.f;
#pragma unroll
            for (int j = 0; j < 4; ++j) {
                p[i][j] = __expf(s[i][j] - mnew);
                rsum += p[i][j];
            }
            rs[i] = rsum;
            lrow[i] *= alpha;
#pragma unroll
            for (int j = 0; j < 4; ++j) acc[i][j] *= alpha;
        }
#pragma unroll
        for (int off = 1; off < 16; off <<= 1)
#pragma unroll
            for (int i = 0; i < 4; ++i)
                rs[i] += __shfl_xor(rs[i], off);
#pragma unroll
        for (int i = 0; i < 4; ++i) lrow[i] += rs[i];
        __syncthreads();   // done reading sKP as K
#pragma unroll
        for (int j = 0; j < 4; ++j) {
            float4 pj = make_float4(p[0][j], p[1][j], p[2][j], p[3][j]);
            *reinterpret_cast<float4*>(&sKP[(tx * 4 + j) * ST + ty * 4]) = pj;
        }
        __syncthreads();
        // O += P.V   (thread owns qi = ty*4+i, dv = tx*4+j)
#pragma unroll 8
        for (int kj = 0; kj < 64; ++kj) {
            float4 pv = *reinterpret_cast<const float4*>(&sKP[kj * ST + ty * 4]);
            float4 vv = *reinterpret_cast<const float4*>(&sVt[kj * ST + tx * 4]);
            float pa[4] = {pv.x, pv.y, pv.z, pv.w};
            float va[4] = {vv.x, vv.y, vv.z, vv.w};
#pragma unroll
            for (int i = 0; i < 4; ++i)
#pragma unroll
                for (int j = 0; j < 4; ++j)
                    acc[i][j] += pa[i] * va[j];
        }
    }
#pragma unroll
    for (int i = 0; i < 4; ++i) {
        float inv = 1.f / lrow[i];
#pragma unroll
        for (int j = 0; j < 4; ++j)
            o[base + (size_t)(tx * 4 + j) * T_LEN + qt0 + ty * 4 + i] = acc[i][j] * inv;
    }
}

// x = LayerNorm_channels(x + y) * g + b   (in-place on x).  Block: 16 t-columns x 16 c-parts.
__global__ __launch_bounds__(256)
void ln_kernel(const float* __restrict__ x, const float* __restrict__ y,
               const float* __restrict__ g, const float* __restrict__ be,
               float* __restrict__ outx)
{
    __shared__ float redS[4][16];
    __shared__ float redS2[4][16];
    const int tid = threadIdx.x;
    const int txi = tid & 15;
    const int cp = tid >> 4;
    const int wv = tid >> 6;
    const int b = blockIdx.y;
    const int t = blockIdx.x * 16 + txi;
    const size_t bbase = (size_t)b * C_CH * T_LEN + t;
    float s = 0.f, s2 = 0.f;
    for (int ci = 0; ci < 32; ++ci) {
        int c = cp * 32 + ci;
        float vv = x[bbase + (size_t)c * T_LEN] + y[bbase + (size_t)c * T_LEN];
        s += vv; s2 += vv * vv;
    }
    s += __shfl_xor(s, 16);  s += __shfl_xor(s, 32);
    s2 += __shfl_xor(s2, 16); s2 += __shfl_xor(s2, 32);
    if ((tid & 63) < 16) { redS[wv][txi] = s; redS2[wv][txi] = s2; }
    __syncthreads();
    float st = redS[0][txi] + redS[1][txi] + redS[2][txi] + redS[3][txi];
    float s2t = redS2[0][txi] + redS2[1][txi] + redS2[2][txi] + redS2[3][txi];
    float mean = st * (1.f / C_CH);
    float var = s2t * (1.f / C_CH) - mean * mean;
    float rstd = rsqrtf(var + 1e-5f);
    for (int ci = 0; ci < 32; ++ci) {
        int c = cp * 32 + ci;
        size_t idx = bbase + (size_t)c * T_LEN;
        float vv = x[idx] + y[idx];
        outx[idx] = (vv - mean) * rstd * g[c] + be[c];
    }
}

// out[b,0,t] = ( mask * sum_c pw[c]*x[b,c,t] + pb ) * mask
__global__ __launch_bounds__(256)
void proj_kernel(const float* __restrict__ x, const float* __restrict__ pw,
                 const float* __restrict__ pb, const float* __restrict__ mask,
                 float* __restrict__ out)
{
    __shared__ float red[4][16];
    const int tid = threadIdx.x;
    const int txi = tid & 15;
    const int cp = tid >> 4;
    const int wv = tid >> 6;
    const int b = blockIdx.y;
    const int t = blockIdx.x * 16 + txi;
    const size_t bbase = (size_t)b * C_CH * T_LEN + t;
    float s = 0.f;
    for (int ci = 0; ci < 32; ++ci) {
        int c = cp * 32 + ci;
        s += pw[c] * x[bbase + (size_t)c * T_LEN];
    }
    s += __shfl_xor(s, 16); s += __shfl_xor(s, 32);
    if ((tid & 63) < 16) red[wv][txi] = s;
    __syncthreads();
    if (tid < 16) {
        float st = red[0][txi] + red[1][txi] + red[2][txi] + red[3][txi];
        float mv = mask[(size_t)b * T_LEN + t];
        out[(size_t)b * T_LEN + t] = (st * mv + pb[0]) * mv;
    }
}

extern "C" void kernel_launch(void* const* d_in, const int* in_sizes, int n_in,
                              void* d_out, int out_size, void* d_ws, size_t ws_size,
                              hipStream_t stream)
{
    const float* x    = (const float*)d_in[0];
    const float* nf0  = (const float*)d_in[1];
    const float* xm   = (const float*)d_in[2];
    const float* spk  = (const float*)d_in[3];
    const float* prw  = (const float*)d_in[4];
    const float* prb  = (const float*)d_in[5];
    const float* f0w  = (const float*)d_in[6];
    const float* f0b  = (const float*)d_in[7];
    const float* cw   = (const float*)d_in[8];
    const float* cb   = (const float*)d_in[9];
    const float* pjw  = (const float*)d_in[10];
    const float* pjb  = (const float*)d_in[11];
    const float* qw   = (const float*)d_in[12];
    const float* qb   = (const float*)d_in[13];
    const float* kw   = (const float*)d_in[14];
    const float* kb   = (const float*)d_in[15];
    const float* vw   = (const float*)d_in[16];
    const float* vb   = (const float*)d_in[17];
    const float* ow   = (const float*)d_in[18];
    const float* ob   = (const float*)d_in[19];
    const float* ln0g = (const float*)d_in[20];
    const float* ln0b = (const float*)d_in[21];
    const float* ln1g = (const float*)d_in[22];
    const float* ln1b = (const float*)d_in[23];
    const float* f1w  = (const float*)d_in[24];
    const float* f1b  = (const float*)d_in[25];
    const float* f2w  = (const float*)d_in[26];
    const float* f2b  = (const float*)d_in[27];
    float* out = (float*)d_out;

    const size_t NCT = (size_t)B_SZ * C_CH * T_LEN;   // 4 Mi elems
    float* ws   = (float*)d_ws;
    float* xbuf = ws;                 // residual stream (B,C,T)
    float* t0   = ws + NCT;           // scratch (B,C,T)
    float* qbf  = ws + 2 * NCT;
    float* kbf  = ws + 3 * NCT;
    float* vbf  = ws + 4 * NCT;
    float* h1   = ws + 5 * NCT;       // (B,FC,T) = 4*NCT
    float* obf  = h1;                 // attention output aliases h1 (disjoint lifetimes)

    dim3 blk(256);
    dim3 gC(T_LEN / BT, C_CH / BM, B_SZ);    // (16,4,4)
    dim3 gF(T_LEN / BT, FC_CH / BM, B_SZ);   // (16,16,4)
    dim3 gLN(T_LEN / 16, B_SZ);

    // t0 = x + cond_w @ spk + cond_b
    conv_gemm<1><<<gC, blk, 0, stream>>>(spk, cw, cb, x, xm, t0, C_CH, S_CH, 0, 0, 0, 0);
    // t0 += f0 conv (pad 1,1)
    f0_add_kernel<<<dim3(T_LEN / 256, C_CH, B_SZ), blk, 0, stream>>>(nf0, f0w, f0b, t0);
    // x = prenet(t0) * mask   (pad 1,1)
    conv_gemm<3><<<gC, blk, 0, stream>>>(t0, prw, prb, nullptr, xm, xbuf, C_CH, C_CH, 1, 0, 0, 1);

    for (int l = 0; l < L_N; ++l) {
        const size_t wo = (size_t)l * C_CH * C_CH, bo = (size_t)l * C_CH;
        conv_gemm<1><<<gC, blk, 0, stream>>>(xbuf, qw + wo, qb + bo, nullptr, xm, qbf, C_CH, C_CH, 0, 0, 0, 0);
        conv_gemm<1><<<gC, blk, 0, stream>>>(xbuf, kw + wo, kb + bo, nullptr, xm, kbf, C_CH, C_CH, 0, 0, 0, 0);
        conv_gemm<1><<<gC, blk, 0, stream>>>(xbuf, vw + wo, vb + bo, nullptr, xm, vbf, C_CH, C_CH, 0, 0, 0, 0);
        flash_attn_kernel<<<dim3(T_LEN / 64, H_N, B_SZ), blk, 0, stream>>>(qbf, kbf, vbf, obf);
        conv_gemm<1><<<gC, blk, 0, stream>>>(obf, ow + wo, ob + bo, nullptr, xm, t0, C_CH, C_CH, 0, 0, 0, 0);
        ln_kernel<<<gLN, blk, 0, stream>>>(xbuf, t0, ln0g + bo, ln0b + bo, xbuf);
        conv_gemm<3><<<gF, blk, 0, stream>>>(xbuf, f1w + (size_t)l * FC_CH * C_CH * KW, f1b + (size_t)l * FC_CH,
                                             nullptr, xm, h1, FC_CH, C_CH, 2, 1, 1, 0);
        conv_gemm<3><<<gC, blk, 0, stream>>>(h1, f2w + (size_t)l * C_CH * FC_CH * KW, f2b + bo,
                                             nullptr, xm, t0, C_CH, FC_CH, 2, 0, 1, 1);
        ln_kernel<<<gLN, blk, 0, stream>>>(xbuf, t0, ln1g + bo, ln1b + bo, xbuf);
    }
    proj_kernel<<<gLN, blk, 0, stream>>>(xbuf, pjw, pjb, xm, out);
}

// Round 2
// 11419.204 us; speedup vs baseline: 2.2275x; 2.2275x over previous
//
#include <hip/hip_runtime.h>
#include <cstdint>
#include <cstddef>

#define T_LEN 2048
#define B_SZ 4
#define C_CH 512
#define H_N 8
#define DK_ 64
#define FC_CH 2048
#define L_N 6
#define KW 3
#define S_CH 256

typedef _Float16 h8 __attribute__((ext_vector_type(8)));
typedef _Float16 h4 __attribute__((ext_vector_type(4)));
typedef float floatx4 __attribute__((ext_vector_type(4)));

// ---------------------------------------------------------------------------
// Transpose [b][Cd][T] -> [b][T][Cd], optionally fusing the f0 prenet conv add
// (x_t[b][t][c] = x[b][c][t] + f0b[c] + sum_k f0w[c][k]*nf0[b][t+k-1]).
// ---------------------------------------------------------------------------
__global__ __launch_bounds__(256)
void transpose_f0(const float* __restrict__ src, float* __restrict__ dst, int Cd,
                  const float* __restrict__ nf0, const float* __restrict__ f0w,
                  const float* __restrict__ f0b, int do_f0)
{
    __shared__ float tile[32][33];
    const int tl = threadIdx.x & 31;
    const int r  = threadIdx.x >> 5;        // 0..7
    const int t00 = blockIdx.x * 32;
    const int c00 = blockIdx.y * 32;
    const int b   = blockIdx.z;
    const float* s0 = src + (size_t)b * Cd * T_LEN;
#pragma unroll
    for (int rr = 0; rr < 4; ++rr) {
        int cl = r + rr * 8;
        tile[cl][tl] = s0[(size_t)(c00 + cl) * T_LEN + t00 + tl];
    }
    __syncthreads();
    float* d0 = dst + (size_t)b * T_LEN * Cd;
    const int cg = c00 + tl;
#pragma unroll
    for (int rr = 0; rr < 4; ++rr) {
        int tlo = r + rr * 8;
        float v = tile[tl][tlo];
        if (do_f0) {
            int tg = t00 + tlo;
            float a = f0b[cg];
#pragma unroll
            for (int k = 0; k < 3; ++k) {
                int gt = tg + k - 1;
                if (gt >= 0 && gt < T_LEN) a += f0w[cg * 3 + k] * nf0[(size_t)b * T_LEN + gt];
            }
            v += a;
        }
        d0[(size_t)(t00 + tlo) * Cd + cg] = v;
    }
}

// ---------------------------------------------------------------------------
// Conv1d-as-GEMM on MFMA (f16 in, fp32 acc).
// in  : [b][T][Cin]   (activations, channel-contiguous)
// W   : [M][Cin][KK]  (KK innermost, matches the reference weight layout)
// out : [b][T][out_stride] at column offset 0 (pass pointer-offset for fused cols)
// out[b,t,m] = act( sum_{c,k} W[m,c,k]*in[b,t+k-pl,c] + bias[m] [+res] ) [*mask]
// 128(m) x 128(t) tile, BK=32, 4 waves of 64x64, 16x16x32 f16 MFMA.
// ---------------------------------------------------------------------------
template<int KK>
__global__ __launch_bounds__(256)
void conv_gemm_mfma(const float* __restrict__ in, const float* __restrict__ W,
                    const float* __restrict__ bias, const float* __restrict__ res,
                    const float* __restrict__ mask, float* __restrict__ out,
                    int M, int Cin, int out_stride, int pl,
                    int do_relu, int mask_in, int mask_out)
{
    __shared__ _Float16 sA[128 * 40];   // [m][c], stride 40 halves (80B, 16B-aligned frags)
    __shared__ _Float16 sB[128 * 40];   // [t][c]
    const int tid = threadIdx.x;
    const int lane = tid & 63;
    const int wid = tid >> 6;
    const int wm = wid >> 1, wt = wid & 1;
    const int t0 = blockIdx.x * 128;
    const int m0 = blockIdx.y * 128;
    const int b  = blockIdx.z;
    const float* inb = in + (size_t)b * T_LEN * Cin;
    const float* mk  = mask + (size_t)b * T_LEN;
    const int r = lane & 15, q = lane >> 4;

    floatx4 acc[4][4];
#pragma unroll
    for (int i = 0; i < 4; ++i)
#pragma unroll
        for (int j = 0; j < 4; ++j)
#pragma unroll
            for (int c = 0; c < 4; ++c) acc[i][j][c] = 0.f;

    const int am  = tid >> 1;            // A-stage: row m, 2 threads/row
    const int acb = (tid & 1) * 16;      // 16 c each
    const int btt = tid >> 3;            // B-stage: row t (32 rows/pass), 8 threads/row
    const int bc4 = (tid & 7) * 4;       // 4 c each

    for (int c0 = 0; c0 < Cin; c0 += 32) {
#pragma unroll
        for (int k = 0; k < KK; ++k) {
            // ---- stage A (weights) 128x32 ----
            {
                _Float16 tmp[16];
                const float* wr = W + (size_t)(m0 + am) * Cin * KK + (size_t)(c0 + acb) * KK + k;
                if (KK == 1) {
#pragma unroll
                    for (int v = 0; v < 4; ++v) {
                        float4 f = *reinterpret_cast<const float4*>(wr + v * 4);
                        tmp[v * 4 + 0] = (_Float16)f.x;
                        tmp[v * 4 + 1] = (_Float16)f.y;
                        tmp[v * 4 + 2] = (_Float16)f.z;
                        tmp[v * 4 + 3] = (_Float16)f.w;
                    }
                } else {
#pragma unroll
                    for (int i2 = 0; i2 < 16; ++i2) tmp[i2] = (_Float16)wr[i2 * KK];
                }
                h8 lo, hi;
#pragma unroll
                for (int i2 = 0; i2 < 8; ++i2) { lo[i2] = tmp[i2]; hi[i2] = tmp[8 + i2]; }
                *reinterpret_cast<h8*>(&sA[am * 40 + acb]) = lo;
                *reinterpret_cast<h8*>(&sA[am * 40 + acb + 8]) = hi;
            }
            // ---- stage B (input) 128x32, rows shifted by tap ----
            const int toff = k - pl;
#pragma unroll
            for (int it = 0; it < 4; ++it) {
                int tt = btt + it * 32;
                int gt = t0 + tt + toff;
                float4 f;
                if (gt >= 0 && gt < T_LEN) {
                    f = *reinterpret_cast<const float4*>(&inb[(size_t)gt * Cin + c0 + bc4]);
                    if (mask_in) {
                        float mv = mk[gt];
                        f.x *= mv; f.y *= mv; f.z *= mv; f.w *= mv;
                    }
                } else { f.x = 0.f; f.y = 0.f; f.z = 0.f; f.w = 0.f; }
                h4 hv;
                hv[0] = (_Float16)f.x; hv[1] = (_Float16)f.y;
                hv[2] = (_Float16)f.z; hv[3] = (_Float16)f.w;
                *reinterpret_cast<h4*>(&sB[tt * 40 + bc4]) = hv;
            }
            __syncthreads();
            // ---- fragments + 16 MFMAs per wave ----
            h8 af[4], bf[4];
#pragma unroll
            for (int im = 0; im < 4; ++im)
                af[im] = *reinterpret_cast<const h8*>(&sA[(wm * 64 + im * 16 + r) * 40 + q * 8]);
#pragma unroll
            for (int jt = 0; jt < 4; ++jt)
                bf[jt] = *reinterpret_cast<const h8*>(&sB[(wt * 64 + jt * 16 + r) * 40 + q * 8]);
#pragma unroll
            for (int im = 0; im < 4; ++im)
#pragma unroll
                for (int jt = 0; jt < 4; ++jt)
                    acc[im][jt] = __builtin_amdgcn_mfma_f32_16x16x32_f16(af[im], bf[jt], acc[im][jt], 0, 0, 0);
            __syncthreads();
        }
    }
    // ---- epilogue: D row = m (quad*4+reg), col = t (lane&15) ----
#pragma unroll
    for (int im = 0; im < 4; ++im) {
        const int mb = m0 + wm * 64 + im * 16 + q * 4;
        const float4 bv = *reinterpret_cast<const float4*>(&bias[mb]);
#pragma unroll
        for (int jt = 0; jt < 4; ++jt) {
            const int t = t0 + wt * 64 + jt * 16 + r;
            const size_t ob = ((size_t)b * T_LEN + t) * out_stride + mb;
            float4 v;
            v.x = acc[im][jt][0] + bv.x;
            v.y = acc[im][jt][1] + bv.y;
            v.z = acc[im][jt][2] + bv.z;
            v.w = acc[im][jt][3] + bv.w;
            if (res) {
                const float4 rv = *reinterpret_cast<const float4*>(&res[ob]);
                v.x += rv.x; v.y += rv.y; v.z += rv.z; v.w += rv.w;
            }
            if (do_relu) {
                v.x = fmaxf(v.x, 0.f); v.y = fmaxf(v.y, 0.f);
                v.z = fmaxf(v.z, 0.f); v.w = fmaxf(v.w, 0.f);
            }
            if (mask_out) {
                const float mv = mk[t];
                v.x *= mv; v.y *= mv; v.z *= mv; v.w *= mv;
            }
            *reinterpret_cast<float4*>(&out[ob]) = v;
        }
    }
}

// ---------------------------------------------------------------------------
// Flash-style causal attention, fp32 VALU. qkv: [b][t][1536] (q|k|v each 512),
// o: [b][t][512]. 64 queries per block, one (b,h) per block. All LDS tiles are
// [row][64] row-major (channel-contiguous global layout -> no transposes).
// ---------------------------------------------------------------------------
__global__ __launch_bounds__(256)
void flash_attn_kernel(const float* __restrict__ qkv, float* __restrict__ o)
{
    constexpr int ST = 68;
    __shared__ float sQ[64 * ST];    // [qi][d]
    __shared__ float sKP[64 * ST];   // K [kj][d], reused as P [qi][s]
    __shared__ float sV[64 * ST];    // [s][d]
    const int tid = threadIdx.x;
    const int tx = tid & 15, ty = tid >> 4;
    const int qt0 = blockIdx.x * 64;
    const int h = blockIdx.y, b = blockIdx.z;
    const float* qb = qkv + (size_t)b * T_LEN * 1536 + h * 64;
    const float* kb = qb + 512;
    const float* vb = qb + 1024;

    for (int id = tid; id < 1024; id += 256) {
        int qi = id >> 4, d4 = (id & 15) * 4;
        *reinterpret_cast<float4*>(&sQ[qi * ST + d4]) =
            *reinterpret_cast<const float4*>(&qb[(size_t)(qt0 + qi) * 1536 + d4]);
    }

    float mrow[4], lrow[4], acc[4][4];
#pragma unroll
    for (int i = 0; i < 4; ++i) {
        mrow[i] = -__builtin_inff();
        lrow[i] = 0.f;
#pragma unroll
        for (int j = 0; j < 4; ++j) acc[i][j] = 0.f;
    }

    for (int kt0 = 0; kt0 <= qt0; kt0 += 64) {
        __syncthreads();   // protect sKP(P)/sV reads of the previous iteration
        for (int id = tid; id < 1024; id += 256) {
            int kj = id >> 4, d4 = (id & 15) * 4;
            *reinterpret_cast<float4*>(&sKP[kj * ST + d4]) =
                *reinterpret_cast<const float4*>(&kb[(size_t)(kt0 + kj) * 1536 + d4]);
            *reinterpret_cast<float4*>(&sV[kj * ST + d4]) =
                *reinterpret_cast<const float4*>(&vb[(size_t)(kt0 + kj) * 1536 + d4]);
        }
        __syncthreads();
        // S = Q.K^T (thread: qi = ty*4+i, kj = tx*4+j), d-blocked
        float sc[4][4];
#pragma unroll
        for (int i = 0; i < 4; ++i)
#pragma unroll
            for (int j = 0; j < 4; ++j) sc[i][j] = 0.f;
        for (int d4 = 0; d4 < 64; d4 += 4) {
            float4 qv[4], kv[4];
#pragma unroll
            for (int i = 0; i < 4; ++i)
                qv[i] = *reinterpret_cast<const float4*>(&sQ[(ty * 4 + i) * ST + d4]);
#pragma unroll
            for (int j = 0; j < 4; ++j)
                kv[j] = *reinterpret_cast<const float4*>(&sKP[(tx * 4 + j) * ST + d4]);
#pragma unroll
            for (int i = 0; i < 4; ++i)
#pragma unroll
                for (int j = 0; j < 4; ++j)
                    sc[i][j] += qv[i].x * kv[j].x + qv[i].y * kv[j].y +
                                qv[i].z * kv[j].z + qv[i].w * kv[j].w;
        }
        // scale + causal mask + online softmax
        float p[4][4], mt[4], rs[4];
#pragma unroll
        for (int i = 0; i < 4; ++i) {
            int gq = qt0 + ty * 4 + i;
            mt[i] = -__builtin_inff();
#pragma unroll
            for (int j = 0; j < 4; ++j) {
                int gk = kt0 + tx * 4 + j;
                float sv = sc[i][j] * 0.125f;
                if (gk > gq) sv = -1e4f;
                sc[i][j] = sv;
                mt[i] = fmaxf(mt[i], sv);
            }
        }
#pragma unroll
        for (int off = 1; off < 16; off <<= 1)
#pragma unroll
            for (int i = 0; i < 4; ++i)
                mt[i] = fmaxf(mt[i], __shfl_xor(mt[i], off));
#pragma unroll
        for (int i = 0; i < 4; ++i) {
            float mnew = fmaxf(mrow[i], mt[i]);
            float alpha = __expf(mrow[i] - mnew);
            mrow[i] = mnew;
            float rsum = 0.f;
#pragma unroll
            for (int j = 0; j < 4; ++j) {
                p[i][j] = __expf(sc[i][j] - mnew);
                rsum += p[i][j];
            }
            rs[i] = rsum;
            lrow[i] *= alpha;
#pragma unroll
            for (int j = 0; j < 4; ++j) acc[i][j] *= alpha;
        }
#pragma unroll
        for (int off = 1; off < 16; off <<= 1)
#pragma unroll
            for (int i = 0; i < 4; ++i)
                rs[i] += __shfl_xor(rs[i], off);
#pragma unroll
        for (int i = 0; i < 4; ++i) lrow[i] += rs[i];
        __syncthreads();   // done reading sKP as K
#pragma unroll
        for (int i = 0; i < 4; ++i) {
            float4 pj; pj.x = p[i][0]; pj.y = p[i][1]; pj.z = p[i][2]; pj.w = p[i][3];
            *reinterpret_cast<float4*>(&sKP[(ty * 4 + i) * ST + tx * 4]) = pj;
        }
        __syncthreads();
        // O += P.V (thread: qi = ty*4+i, d = tx*4+j), s-blocked
        for (int s4 = 0; s4 < 64; s4 += 4) {
            float4 pv[4], vv[4];
#pragma unroll
            for (int i = 0; i < 4; ++i)
                pv[i] = *reinterpret_cast<const float4*>(&sKP[(ty * 4 + i) * ST + s4]);
#pragma unroll
            for (int rr = 0; rr < 4; ++rr)
                vv[rr] = *reinterpret_cast<const float4*>(&sV[(s4 + rr) * ST + tx * 4]);
#pragma unroll
            for (int i = 0; i < 4; ++i) {
                acc[i][0] += pv[i].x * vv[0].x + pv[i].y * vv[1].x + pv[i].z * vv[2].x + pv[i].w * vv[3].x;
                acc[i][1] += pv[i].x * vv[0].y + pv[i].y * vv[1].y + pv[i].z * vv[2].y + pv[i].w * vv[3].y;
                acc[i][2] += pv[i].x * vv[0].z + pv[i].y * vv[1].z + pv[i].z * vv[2].z + pv[i].w * vv[3].z;
                acc[i][3] += pv[i].x * vv[0].w + pv[i].y * vv[1].w + pv[i].z * vv[2].w + pv[i].w * vv[3].w;
            }
        }
    }
    float* ob = o + (size_t)b * T_LEN * C_CH + h * 64;
#pragma unroll
    for (int i = 0; i < 4; ++i) {
        float inv = 1.f / lrow[i];
        float4 v;
        v.x = acc[i][0] * inv; v.y = acc[i][1] * inv;
        v.z = acc[i][2] * inv; v.w = acc[i][3] * inv;
        *reinterpret_cast<float4*>(&ob[(size_t)(qt0 + ty * 4 + i) * C_CH + tx * 4]) = v;
    }
}

// ---------------------------------------------------------------------------
// Channel LayerNorm, [b][t][512] layout: one wave per t-row.
// outx[b,t,:] = LN(x[b,t,:] + y[b,t,:]) * g + be
// ---------------------------------------------------------------------------
__global__ __launch_bounds__(256)
void ln_kernel(const float* __restrict__ x, const float* __restrict__ y,
               const float* __restrict__ g, const float* __restrict__ be,
               float* __restrict__ outx)
{
    const int w = threadIdx.x >> 6, lane = threadIdx.x & 63;
    const int t = blockIdx.x * 4 + w, b = blockIdx.y;
    const size_t base = ((size_t)b * T_LEN + t) * C_CH + lane * 8;
    float4 x0 = *reinterpret_cast<const float4*>(&x[base]);
    float4 x1 = *reinterpret_cast<const float4*>(&x[base + 4]);
    float4 y0 = *reinterpret_cast<const float4*>(&y[base]);
    float4 y1 = *reinterpret_cast<const float4*>(&y[base + 4]);
    float v[8] = {x0.x + y0.x, x0.y + y0.y, x0.z + y0.z, x0.w + y0.w,
                  x1.x + y1.x, x1.y + y1.y, x1.z + y1.z, x1.w + y1.w};
    float s = 0.f, s2 = 0.f;
#pragma unroll
    for (int i = 0; i < 8; ++i) { s += v[i]; s2 += v[i] * v[i]; }
#pragma unroll
    for (int off = 1; off < 64; off <<= 1) {
        s  += __shfl_xor(s, off);
        s2 += __shfl_xor(s2, off);
    }
    const float mean = s * (1.f / C_CH);
    const float var  = s2 * (1.f / C_CH) - mean * mean;
    const float rstd = rsqrtf(var + 1e-5f);
    float4 g0 = *reinterpret_cast<const float4*>(&g[lane * 8]);
    float4 g1 = *reinterpret_cast<const float4*>(&g[lane * 8 + 4]);
    float4 b0 = *reinterpret_cast<const float4*>(&be[lane * 8]);
    float4 b1 = *reinterpret_cast<const float4*>(&be[lane * 8 + 4]);
    float4 o0, o1;
    o0.x = (v[0] - mean) * rstd * g0.x + b0.x;
    o0.y = (v[1] - mean) * rstd * g0.y + b0.y;
    o0.z = (v[2] - mean) * rstd * g0.z + b0.z;
    o0.w = (v[3] - mean) * rstd * g0.w + b0.w;
    o1.x = (v[4] - mean) * rstd * g1.x + b1.x;
    o1.y = (v[5] - mean) * rstd * g1.y + b1.y;
    o1.z = (v[6] - mean) * rstd * g1.z + b1.z;
    o1.w = (v[7] - mean) * rstd * g1.w + b1.w;
    *reinterpret_cast<float4*>(&outx[base])     = o0;
    *reinterpret_cast<float4*>(&outx[base + 4]) = o1;
}

// out[b,t] = ( mask * sum_c pw[c]*x[b,t,c] + pb ) * mask   (one wave per t)
__global__ __launch_bounds__(256)
void proj_kernel(const float* __restrict__ x, const float* __restrict__ pw,
                 const float* __restrict__ pb, const float* __restrict__ mask,
                 float* __restrict__ out)
{
    const int w = threadIdx.x >> 6, lane = threadIdx.x & 63;
    const int t = blockIdx.x * 4 + w, b = blockIdx.y;
    const size_t base = ((size_t)b * T_LEN + t) * C_CH + lane * 8;
    float4 x0 = *reinterpret_cast<const float4*>(&x[base]);
    float4 x1 = *reinterpret_cast<const float4*>(&x[base + 4]);
    float4 p0 = *reinterpret_cast<const float4*>(&pw[lane * 8]);
    float4 p1 = *reinterpret_cast<const float4*>(&pw[lane * 8 + 4]);
    float s = x0.x * p0.x + x0.y * p0.y + x0.z * p0.z + x0.w * p0.w +
              x1.x * p1.x + x1.y * p1.y + x1.z * p1.z + x1.w * p1.w;
#pragma unroll
    for (int off = 1; off < 64; off <<= 1) s += __shfl_xor(s, off);
    if (lane == 0) {
        const float mv = mask[(size_t)b * T_LEN + t];
        out[(size_t)b * T_LEN + t] = (s * mv + pb[0]) * mv;
    }
}

extern "C" void kernel_launch(void* const* d_in, const int* in_sizes, int n_in,
                              void* d_out, int out_size, void* d_ws, size_t ws_size,
                              hipStream_t stream)
{
    const float* x    = (const float*)d_in[0];
    const float* nf0  = (const float*)d_in[1];
    const float* xm   = (const float*)d_in[2];
    const float* spk  = (const float*)d_in[3];
    const float* prw  = (const float*)d_in[4];
    const float* prb  = (const float*)d_in[5];
    const float* f0w  = (const float*)d_in[6];
    const float* f0b  = (const float*)d_in[7];
    const float* cw   = (const float*)d_in[8];
    const float* cb   = (const float*)d_in[9];
    const float* pjw  = (const float*)d_in[10];
    const float* pjb  = (const float*)d_in[11];
    const float* qw   = (const float*)d_in[12];
    const float* qb   = (const float*)d_in[13];
    const float* kw   = (const float*)d_in[14];
    const float* kb   = (const float*)d_in[15];
    const float* vw   = (const float*)d_in[16];
    const float* vb   = (const float*)d_in[17];
    const float* ow   = (const float*)d_in[18];
    const float* ob   = (const float*)d_in[19];
    const float* ln0g = (const float*)d_in[20];
    const float* ln0b = (const float*)d_in[21];
    const float* ln1g = (const float*)d_in[22];
    const float* ln1b = (const float*)d_in[23];
    const float* f1w  = (const float*)d_in[24];
    const float* f1b  = (const float*)d_in[25];
    const float* f2w  = (const float*)d_in[26];
    const float* f2b  = (const float*)d_in[27];
    float* out = (float*)d_out;

    const size_t NCT = (size_t)B_SZ * C_CH * T_LEN;   // 4.19M floats
    float* ws   = (float*)d_ws;
    float* xbuf = ws;                  // [b][t][512] residual stream
    float* t0   = ws + NCT;            // [b][t][512] scratch
    float* qkv  = ws + 2 * NCT;        // [b][t][1536]
    float* h1   = ws + 5 * NCT;        // [b][t][2048]
    float* spkT = qkv;                 // [b][t][256]  (dead before qkv written)
    float* xT   = h1;                  // [b][t][512]  (dead before h1/obf written)
    float* obf  = h1;                  // [b][t][512]  (dead before ffn1 writes h1)

    dim3 blk(256);
    dim3 gC(16, 4, B_SZ);              // M=512 conv tiles
    dim3 gF(16, 16, B_SZ);             // M=2048 conv tiles
    dim3 gLN(T_LEN / 4, B_SZ);

    // x_t = transpose(x) + f0 conv;  spk_t = transpose(spk)
    transpose_f0<<<dim3(64, 16, B_SZ), blk, 0, stream>>>(x, xT, C_CH, nf0, f0w, f0b, 1);
    transpose_f0<<<dim3(64, 8, B_SZ), blk, 0, stream>>>(spk, spkT, S_CH, nullptr, nullptr, nullptr, 0);
    // t0 = cond(spk) + x_t
    conv_gemm_mfma<1><<<gC, blk, 0, stream>>>(spkT, cw, cb, xT, xm, t0, C_CH, S_CH, C_CH, 0, 0, 0, 0);
    // xbuf = prenet(t0) * mask
    conv_gemm_mfma<3><<<gC, blk, 0, stream>>>(t0, prw, prb, nullptr, xm, xbuf, C_CH, C_CH, C_CH, 1, 0, 0, 1);

    for (int l = 0; l < L_N; ++l) {
        const size_t wo = (size_t)l * C_CH * C_CH, bo = (size_t)l * C_CH;
        conv_gemm_mfma<1><<<gC, blk, 0, stream>>>(xbuf, qw + wo, qb + bo, nullptr, xm, qkv,        C_CH, C_CH, 1536, 0, 0, 0, 0);
        conv_gemm_mfma<1><<<gC, blk, 0, stream>>>(xbuf, kw + wo, kb + bo, nullptr, xm, qkv + 512,  C_CH, C_CH, 1536, 0, 0, 0, 0);
        conv_gemm_mfma<1><<<gC, blk, 0, stream>>>(xbuf, vw + wo, vb + bo, nullptr, xm, qkv + 1024, C_CH, C_CH, 1536, 0, 0, 0, 0);
        flash_attn_kernel<<<dim3(32, H_N, B_SZ), blk, 0, stream>>>(qkv, obf);
        conv_gemm_mfma<1><<<gC, blk, 0, stream>>>(obf, ow + wo, ob + bo, nullptr, xm, t0, C_CH, C_CH, C_CH, 0, 0, 0, 0);
        ln_kernel<<<gLN, blk, 0, stream>>>(xbuf, t0, ln0g + bo, ln0b + bo, xbuf);
        conv_gemm_mfma<3><<<gF, blk, 0, stream>>>(xbuf, f1w + (size_t)l * FC_CH * C_CH * KW, f1b + (size_t)l * FC_CH,
                                                  nullptr, xm, h1, FC_CH, C_CH, FC_CH, 2, 1, 1, 0);
        conv_gemm_mfma<3><<<gC, blk, 0, stream>>>(h1, f2w + (size_t)l * C_CH * FC_CH * KW, f2b + bo,
                                                  nullptr, xm, t0, C_CH, FC_CH, C_CH, 2, 0, 1, 1);
        ln_kernel<<<gLN, blk, 0, stream>>>(xbuf, t0, ln1g + bo, ln1b + bo, xbuf);
    }
    proj_kernel<<<gLN, blk, 0, stream>>>(xbuf, pjw, pjb, xm, out);
}

// Round 3
// 3259.439 us; speedup vs baseline: 7.8037x; 3.5034x over previous
//
#include <hip/hip_runtime.h>
#include <cstdint>
#include <cstddef>

#define T_LEN 2048
#define B_SZ 4
#define C_CH 512
#define H_N 8
#define DK_ 64
#define FC_CH 2048
#define L_N 6
#define KW 3
#define S_CH 256

typedef _Float16 h8 __attribute__((ext_vector_type(8)));
typedef _Float16 h4 __attribute__((ext_vector_type(4)));
typedef float floatx4 __attribute__((ext_vector_type(4)));

// ---------------------------------------------------------------------------
// Weight prepack kernels (run every call; weights -> f16 in ws).
// ---------------------------------------------------------------------------
__global__ __launch_bounds__(256)
void cast_f16(const float* __restrict__ src, _Float16* __restrict__ dst, int n)
{
    int i = blockIdx.x * 256 + threadIdx.x;
    if (i < n) dst[i] = (_Float16)src[i];
}

// src [row][c][k] (k fastest, K=3) -> dst [row][c0blk][k][cl]  (32-channel chunks,
// taps separated so MFMA A-fragments are contiguous per tap)
__global__ __launch_bounds__(256)
void prepack_k3(const float* __restrict__ src, _Float16* __restrict__ dst,
                int Cin, int total)
{
    int i = blockIdx.x * 256 + threadIdx.x;
    if (i >= total) return;
    const int rk = Cin * 3;
    int row = i / rk, o = i - row * rk;
    int blk = o / 96, rr = o - blk * 96;
    int k = rr >> 5, cl = rr & 31;
    dst[i] = (_Float16)src[(size_t)row * rk + (size_t)(blk * 32 + cl) * 3 + k];
}

// concat q|k|v weights into [l][1536][512] f16 + biases into [l][1536] f32
__global__ __launch_bounds__(256)
void prepack_qkv(const float* __restrict__ qw, const float* __restrict__ kw,
                 const float* __restrict__ vw, const float* __restrict__ qb,
                 const float* __restrict__ kb, const float* __restrict__ vb,
                 _Float16* __restrict__ dst, float* __restrict__ bdst)
{
    int i = blockIdx.x * 256 + threadIdx.x;
    const int total = L_N * 1536 * 512;
    if (i < total) {
        int l = i / (1536 * 512);
        int o = i - l * (1536 * 512);
        int m = o >> 9, c = o & 511;
        const float* s = (m < 512) ? qw : ((m < 1024) ? kw : vw);
        dst[i] = (_Float16)s[((size_t)l * 512 + (m & 511)) * 512 + c];
    }
    if (i < L_N * 1536) {
        int l = i / 1536, m = i - l * 1536;
        const float* s = (m < 512) ? qb : ((m < 1024) ? kb : vb);
        bdst[i] = s[l * 512 + (m & 511)];
    }
}

// ---------------------------------------------------------------------------
// Transpose [b][Cd][T] -> [b][T][Cd], optionally fusing the f0 conv add.
// ---------------------------------------------------------------------------
__global__ __launch_bounds__(256)
void transpose_f0(const float* __restrict__ src, float* __restrict__ dst, int Cd,
                  const float* __restrict__ nf0, const float* __restrict__ f0w,
                  const float* __restrict__ f0b, int do_f0)
{
    __shared__ float tile[32][33];
    const int tl = threadIdx.x & 31;
    const int r  = threadIdx.x >> 5;
    const int t00 = blockIdx.x * 32;
    const int c00 = blockIdx.y * 32;
    const int b   = blockIdx.z;
    const float* s0 = src + (size_t)b * Cd * T_LEN;
#pragma unroll
    for (int rr = 0; rr < 4; ++rr) {
        int cl = r + rr * 8;
        tile[cl][tl] = s0[(size_t)(c00 + cl) * T_LEN + t00 + tl];
    }
    __syncthreads();
    float* d0 = dst + (size_t)b * T_LEN * Cd;
    const int cg = c00 + tl;
#pragma unroll
    for (int rr = 0; rr < 4; ++rr) {
        int tlo = r + rr * 8;
        float v = tile[tl][tlo];
        if (do_f0) {
            int tg = t00 + tlo;
            float a = f0b[cg];
#pragma unroll
            for (int k = 0; k < 3; ++k) {
                int gt = tg + k - 1;
                if (gt >= 0 && gt < T_LEN) a += f0w[cg * 3 + k] * nf0[(size_t)b * T_LEN + gt];
            }
            v += a;
        }
        d0[(size_t)(t00 + tlo) * Cd + cg] = v;
    }
}

// ---------------------------------------------------------------------------
// Conv1d-as-GEMM on MFMA, prepacked f16 weights.
// in: [b][T][Cin] (f32 or f16 per INF16); out: [b][T][out_stride] (f32/f16).
// Single barrier pair per 32-channel chunk; KK taps computed from one staged
// B tile (halo rows) + per-tap A sections. 48 (KK=3) MFMAs per barrier/wave.
// ---------------------------------------------------------------------------
template<int KK, int INF16, int OUTF16>
__global__ __launch_bounds__(256)
void conv_gemm_mfma(const void* __restrict__ in_v, const _Float16* __restrict__ Wpk,
                    const float* __restrict__ bias, const float* __restrict__ res,
                    const float* __restrict__ mask, void* __restrict__ out_v,
                    int Cin, int out_stride, int pl, int do_relu,
                    int mask_in, int mask_out)
{
    constexpr int CKW  = 32 * KK;          // 96 or 32
    constexpr int AST  = CKW + 8;          // 104 or 40 halves (odd x 16B -> no conflicts)
    constexpr int HALO = (KK == 3) ? 2 : 0;
    constexpr int RB   = 128 + 2 * HALO;   // staged B rows
    __shared__ _Float16 sA[128 * AST];
    __shared__ _Float16 sB[RB * 40];

    const int tid = threadIdx.x;
    const int lane = tid & 63;
    const int wid = tid >> 6;
    const int wm = wid >> 1, wt = wid & 1;
    const int r = lane & 15, q4 = lane >> 4;
    const int t0 = blockIdx.x * 128;
    const int m0 = blockIdx.y * 128;
    const int b  = blockIdx.z;
    const float* mk = mask + (size_t)b * T_LEN;

    floatx4 acc[4][4];
#pragma unroll
    for (int i = 0; i < 4; ++i)
#pragma unroll
        for (int j = 0; j < 4; ++j)
#pragma unroll
            for (int c = 0; c < 4; ++c) acc[i][j][c] = 0.f;

    for (int c0 = 0; c0 < Cin; c0 += 32) {
        // ---- stage A: straight f16 copies (layout matches prepack) ----
        {
            const int row = tid >> 1;
            const int h0 = (tid & 1) * (CKW / 2);
            const _Float16* src = Wpk + (size_t)(m0 + row) * (Cin * KK) + (size_t)c0 * KK + h0;
            _Float16* dstp = &sA[row * AST + h0];
#pragma unroll
            for (int j = 0; j < CKW / 16; ++j)
                *reinterpret_cast<h8*>(dstp + j * 8) = *reinterpret_cast<const h8*>(src + j * 8);
        }
        // ---- stage B with halo rows ----
        if (INF16) {
            const _Float16* in_h = (const _Float16*)in_v + (size_t)b * T_LEN * Cin;
            for (int id = tid; id < RB * 4; id += 256) {
                int row = id >> 2, c8 = (id & 3) * 8;
                int gt = t0 + row - HALO;
                h8 hv;
                if (gt >= 0 && gt < T_LEN) {
                    hv = *reinterpret_cast<const h8*>(&in_h[(size_t)gt * Cin + c0 + c8]);
                    if (mask_in) { _Float16 mv = (_Float16)mk[gt]; hv *= mv; }
                } else {
#pragma unroll
                    for (int j = 0; j < 8; ++j) hv[j] = (_Float16)0.f;
                }
                *reinterpret_cast<h8*>(&sB[row * 40 + c8]) = hv;
            }
        } else {
            const float* in_f = (const float*)in_v + (size_t)b * T_LEN * Cin;
            for (int id = tid; id < RB * 8; id += 256) {
                int row = id >> 3, c4 = (id & 7) * 4;
                int gt = t0 + row - HALO;
                h4 hv;
                if (gt >= 0 && gt < T_LEN) {
                    float4 f = *reinterpret_cast<const float4*>(&in_f[(size_t)gt * Cin + c0 + c4]);
                    if (mask_in) { float mv = mk[gt]; f.x *= mv; f.y *= mv; f.z *= mv; f.w *= mv; }
                    hv[0] = (_Float16)f.x; hv[1] = (_Float16)f.y;
                    hv[2] = (_Float16)f.z; hv[3] = (_Float16)f.w;
                } else {
#pragma unroll
                    for (int j = 0; j < 4; ++j) hv[j] = (_Float16)0.f;
                }
                *reinterpret_cast<h4*>(&sB[row * 40 + c4]) = hv;
            }
        }
        __syncthreads();
        // ---- KK taps x 16 MFMA ----
#pragma unroll
        for (int k = 0; k < KK; ++k) {
            h8 af[4], bf[4];
#pragma unroll
            for (int im = 0; im < 4; ++im)
                af[im] = *reinterpret_cast<const h8*>(&sA[(wm * 64 + im * 16 + r) * AST + k * 32 + q4 * 8]);
            const int rb0 = wt * 64 + r + k - pl + HALO;
#pragma unroll
            for (int jt = 0; jt < 4; ++jt)
                bf[jt] = *reinterpret_cast<const h8*>(&sB[(rb0 + jt * 16) * 40 + q4 * 8]);
#pragma unroll
            for (int im = 0; im < 4; ++im)
#pragma unroll
                for (int jt = 0; jt < 4; ++jt)
                    acc[im][jt] = __builtin_amdgcn_mfma_f32_16x16x32_f16(af[im], bf[jt], acc[im][jt], 0, 0, 0);
        }
        __syncthreads();
    }
    // ---- epilogue: D row = m (q4*4+reg), col = t (lane&15) ----
#pragma unroll
    for (int im = 0; im < 4; ++im) {
        const int mb = m0 + wm * 64 + im * 16 + q4 * 4;
        const float4 bv = *reinterpret_cast<const float4*>(&bias[mb]);
#pragma unroll
        for (int jt = 0; jt < 4; ++jt) {
            const int t = t0 + wt * 64 + jt * 16 + r;
            const size_t ob = ((size_t)b * T_LEN + t) * out_stride + mb;
            float4 v;
            v.x = acc[im][jt][0] + bv.x;
            v.y = acc[im][jt][1] + bv.y;
            v.z = acc[im][jt][2] + bv.z;
            v.w = acc[im][jt][3] + bv.w;
            if (res) {
                const float4 rv = *reinterpret_cast<const float4*>(&res[ob]);
                v.x += rv.x; v.y += rv.y; v.z += rv.z; v.w += rv.w;
            }
            if (do_relu) {
                v.x = fmaxf(v.x, 0.f); v.y = fmaxf(v.y, 0.f);
                v.z = fmaxf(v.z, 0.f); v.w = fmaxf(v.w, 0.f);
            }
            if (mask_out) {
                const float mv = mk[t];
                v.x *= mv; v.y *= mv; v.z *= mv; v.w *= mv;
            }
            if (OUTF16) {
                h4 hv;
                hv[0] = (_Float16)v.x; hv[1] = (_Float16)v.y;
                hv[2] = (_Float16)v.z; hv[3] = (_Float16)v.w;
                *reinterpret_cast<h4*>((_Float16*)out_v + ob) = hv;
            } else {
                *reinterpret_cast<float4*>((float*)out_v + ob) = v;
            }
        }
    }
}

// ---------------------------------------------------------------------------
// MFMA flash attention (f16 QK^T / PV, fp32 online softmax + accum).
// qkv: [b][t][1536] f16 (q|k|v); o: [b][t][512] f16. Q-tile 128 (32/wave),
// K-tile 64. P round-trips through LDS (C-layout -> A-layout).
// ---------------------------------------------------------------------------
__global__ __launch_bounds__(256)
void flash_attn_mfma(const _Float16* __restrict__ qkv, _Float16* __restrict__ o)
{
    __shared__ _Float16 sK[64 * 72];    // [s][d]
    __shared__ _Float16 sVt[64 * 72];   // [d][s]
    __shared__ _Float16 sP[128 * 72];   // [q][s]
    const int tid = threadIdx.x;
    const int lane = tid & 63;
    const int w = tid >> 6;
    const int r = lane & 15, q4 = lane >> 4;
    const int qt0 = blockIdx.x * 128;
    const int h = blockIdx.y, b = blockIdx.z;
    const size_t tb = (size_t)b * T_LEN;
    const int hq = h * 64, hk = 512 + h * 64, hv = 1024 + h * 64;

    // Q fragments (resident whole kernel), pre-scaled by 1/sqrt(64)=0.125 (exact in f16)
    h8 qf[2][2];
#pragma unroll
    for (int im = 0; im < 2; ++im)
#pragma unroll
        for (int dc = 0; dc < 2; ++dc) {
            h8 t = *reinterpret_cast<const h8*>(
                &qkv[(tb + qt0 + w * 32 + im * 16 + r) * 1536 + hq + dc * 32 + q4 * 8]);
            qf[im][dc] = t * (_Float16)0.125f;
        }

    floatx4 oacc[2][4];
    float mrow[2][4], lrow[2][4];
#pragma unroll
    for (int im = 0; im < 2; ++im)
#pragma unroll
        for (int reg = 0; reg < 4; ++reg) {
            mrow[im][reg] = -__builtin_inff();
            lrow[im][reg] = 0.f;
        }
#pragma unroll
    for (int im = 0; im < 2; ++im)
#pragma unroll
        for (int jd = 0; jd < 4; ++jd)
#pragma unroll
            for (int c = 0; c < 4; ++c) oacc[im][jd][c] = 0.f;

    const int qhi = qt0 + w * 32 + 31;
    const int nk = (qt0 >> 6) + 2;
    for (int kt = 0; kt < nk; ++kt) {
        const int kt0 = kt * 64;
        __syncthreads();   // previous iteration's sK/sVt reads done
        {   // stage K: 64 x 64 halves, 1 pass
            int row = tid >> 2, c16 = (tid & 3) * 16;
            const _Float16* src = &qkv[(tb + kt0 + row) * 1536 + hk + c16];
            *reinterpret_cast<h8*>(&sK[row * 72 + c16]) = *reinterpret_cast<const h8*>(src);
            *reinterpret_cast<h8*>(&sK[row * 72 + c16 + 8]) = *reinterpret_cast<const h8*>(src + 8);
        }
#pragma unroll
        for (int p = 0; p < 2; ++p) {   // stage V transposed
            int id = p * 256 + tid;
            int s = id >> 3, d8 = (id & 7) * 8;
            h8 t = *reinterpret_cast<const h8*>(&qkv[(tb + kt0 + s) * 1536 + hv + d8]);
#pragma unroll
            for (int j = 0; j < 8; ++j) sVt[(d8 + j) * 72 + s] = t[j];
        }
        __syncthreads();
        if (kt0 <= qhi) {
            // ---- S = Q.K^T ----
            floatx4 sacc[2][4];
#pragma unroll
            for (int im = 0; im < 2; ++im)
#pragma unroll
                for (int js = 0; js < 4; ++js)
#pragma unroll
                    for (int c = 0; c < 4; ++c) sacc[im][js][c] = 0.f;
#pragma unroll
            for (int dc = 0; dc < 2; ++dc) {
                h8 kf[4];
#pragma unroll
                for (int js = 0; js < 4; ++js)
                    kf[js] = *reinterpret_cast<const h8*>(&sK[(js * 16 + r) * 72 + dc * 32 + q4 * 8]);
#pragma unroll
                for (int im = 0; im < 2; ++im)
#pragma unroll
                    for (int js = 0; js < 4; ++js)
                        sacc[im][js] = __builtin_amdgcn_mfma_f32_16x16x32_f16(qf[im][dc], kf[js], sacc[im][js], 0, 0, 0);
            }
            // ---- causal mask + online softmax (rows: im*16+q4*4+reg, cols: js*16+r) ----
#pragma unroll
            for (int im = 0; im < 2; ++im)
#pragma unroll
                for (int js = 0; js < 4; ++js) {
                    const int s_g = kt0 + js * 16 + r;
#pragma unroll
                    for (int reg = 0; reg < 4; ++reg) {
                        const int q_g = qt0 + w * 32 + im * 16 + q4 * 4 + reg;
                        if (s_g > q_g) sacc[im][js][reg] = -1e4f;
                    }
                }
            float mt[2][4];
#pragma unroll
            for (int im = 0; im < 2; ++im)
#pragma unroll
                for (int reg = 0; reg < 4; ++reg) {
                    float m0v = fmaxf(fmaxf(sacc[im][0][reg], sacc[im][1][reg]),
                                      fmaxf(sacc[im][2][reg], sacc[im][3][reg]));
#pragma unroll
                    for (int off = 1; off < 16; off <<= 1)
                        m0v = fmaxf(m0v, __shfl_xor(m0v, off));
                    mt[im][reg] = m0v;
                }
            float alpha[2][4];
#pragma unroll
            for (int im = 0; im < 2; ++im)
#pragma unroll
                for (int reg = 0; reg < 4; ++reg) {
                    float mn = fmaxf(mrow[im][reg], mt[im][reg]);
                    alpha[im][reg] = __expf(mrow[im][reg] - mn);
                    mrow[im][reg] = mn;
                    float rs = 0.f;
#pragma unroll
                    for (int js = 0; js < 4; ++js) {
                        float p = __expf(sacc[im][js][reg] - mn);
                        sacc[im][js][reg] = p;
                        rs += p;
                    }
#pragma unroll
                    for (int off = 1; off < 16; off <<= 1)
                        rs += __shfl_xor(rs, off);
                    lrow[im][reg] = lrow[im][reg] * alpha[im][reg] + rs;
                }
#pragma unroll
            for (int im = 0; im < 2; ++im)
#pragma unroll
                for (int jd = 0; jd < 4; ++jd)
#pragma unroll
                    for (int reg = 0; reg < 4; ++reg)
                        oacc[im][jd][reg] *= alpha[im][reg];
            // ---- P -> LDS (C-layout scatter), per-wave region, no barrier needed ----
#pragma unroll
            for (int im = 0; im < 2; ++im)
#pragma unroll
                for (int js = 0; js < 4; ++js)
#pragma unroll
                    for (int reg = 0; reg < 4; ++reg)
                        sP[(w * 32 + im * 16 + q4 * 4 + reg) * 72 + js * 16 + r] =
                            (_Float16)sacc[im][js][reg];
            // ---- O += P.V ----
#pragma unroll
            for (int sc = 0; sc < 2; ++sc) {
                h8 pf[2], vf[4];
#pragma unroll
                for (int im = 0; im < 2; ++im)
                    pf[im] = *reinterpret_cast<const h8*>(&sP[(w * 32 + im * 16 + r) * 72 + sc * 32 + q4 * 8]);
#pragma unroll
                for (int jd = 0; jd < 4; ++jd)
                    vf[jd] = *reinterpret_cast<const h8*>(&sVt[(jd * 16 + r) * 72 + sc * 32 + q4 * 8]);
#pragma unroll
                for (int im = 0; im < 2; ++im)
#pragma unroll
                    for (int jd = 0; jd < 4; ++jd)
                        oacc[im][jd] = __builtin_amdgcn_mfma_f32_16x16x32_f16(pf[im], vf[jd], oacc[im][jd], 0, 0, 0);
            }
        }
    }
    // ---- normalize + store (f16) ----
#pragma unroll
    for (int im = 0; im < 2; ++im)
#pragma unroll
        for (int reg = 0; reg < 4; ++reg) {
            const float inv = 1.f / lrow[im][reg];
            const size_t rowb = (tb + qt0 + w * 32 + im * 16 + q4 * 4 + reg) * 512 + h * 64 + r;
#pragma unroll
            for (int jd = 0; jd < 4; ++jd)
                o[rowb + jd * 16] = (_Float16)(oacc[im][jd][reg] * inv);
        }
}

// ---------------------------------------------------------------------------
// Channel LayerNorm on [b][t][512]: one wave per t-row. outx = LN(x+y)*g+be
// ---------------------------------------------------------------------------
__global__ __launch_bounds__(256)
void ln_kernel(const float* __restrict__ x, const float* __restrict__ y,
               const float* __restrict__ g, const float* __restrict__ be,
               float* __restrict__ outx)
{
    const int w = threadIdx.x >> 6, lane = threadIdx.x & 63;
    const int t = blockIdx.x * 4 + w, b = blockIdx.y;
    const size_t base = ((size_t)b * T_LEN + t) * C_CH + lane * 8;
    float4 x0 = *reinterpret_cast<const float4*>(&x[base]);
    float4 x1 = *reinterpret_cast<const float4*>(&x[base + 4]);
    float4 y0 = *reinterpret_cast<const float4*>(&y[base]);
    float4 y1 = *reinterpret_cast<const float4*>(&y[base + 4]);
    float v[8] = {x0.x + y0.x, x0.y + y0.y, x0.z + y0.z, x0.w + y0.w,
                  x1.x + y1.x, x1.y + y1.y, x1.z + y1.z, x1.w + y1.w};
    float s = 0.f, s2 = 0.f;
#pragma unroll
    for (int i = 0; i < 8; ++i) { s += v[i]; s2 += v[i] * v[i]; }
#pragma unroll
    for (int off = 1; off < 64; off <<= 1) {
        s  += __shfl_xor(s, off);
        s2 += __shfl_xor(s2, off);
    }
    const float mean = s * (1.f / C_CH);
    const float var  = s2 * (1.f / C_CH) - mean * mean;
    const float rstd = rsqrtf(var + 1e-5f);
    float4 g0 = *reinterpret_cast<const float4*>(&g[lane * 8]);
    float4 g1 = *reinterpret_cast<const float4*>(&g[lane * 8 + 4]);
    float4 b0 = *reinterpret_cast<const float4*>(&be[lane * 8]);
    float4 b1 = *reinterpret_cast<const float4*>(&be[lane * 8 + 4]);
    float4 o0, o1;
    o0.x = (v[0] - mean) * rstd * g0.x + b0.x;
    o0.y = (v[1] - mean) * rstd * g0.y + b0.y;
    o0.z = (v[2] - mean) * rstd * g0.z + b0.z;
    o0.w = (v[3] - mean) * rstd * g0.w + b0.w;
    o1.x = (v[4] - mean) * rstd * g1.x + b1.x;
    o1.y = (v[5] - mean) * rstd * g1.y + b1.y;
    o1.z = (v[6] - mean) * rstd * g1.z + b1.z;
    o1.w = (v[7] - mean) * rstd * g1.w + b1.w;
    *reinterpret_cast<float4*>(&outx[base])     = o0;
    *reinterpret_cast<float4*>(&outx[base + 4]) = o1;
}

// out[b,t] = ( mask * sum_c pw[c]*x[b,t,c] + pb ) * mask   (one wave per t)
__global__ __launch_bounds__(256)
void proj_kernel(const float* __restrict__ x, const float* __restrict__ pw,
                 const float* __restrict__ pb, const float* __restrict__ mask,
                 float* __restrict__ out)
{
    const int w = threadIdx.x >> 6, lane = threadIdx.x & 63;
    const int t = blockIdx.x * 4 + w, b = blockIdx.y;
    const size_t base = ((size_t)b * T_LEN + t) * C_CH + lane * 8;
    float4 x0 = *reinterpret_cast<const float4*>(&x[base]);
    float4 x1 = *reinterpret_cast<const float4*>(&x[base + 4]);
    float4 p0 = *reinterpret_cast<const float4*>(&pw[lane * 8]);
    float4 p1 = *reinterpret_cast<const float4*>(&pw[lane * 8 + 4]);
    float s = x0.x * p0.x + x0.y * p0.y + x0.z * p0.z + x0.w * p0.w +
              x1.x * p1.x + x1.y * p1.y + x1.z * p1.z + x1.w * p1.w;
#pragma unroll
    for (int off = 1; off < 64; off <<= 1) s += __shfl_xor(s, off);
    if (lane == 0) {
        const float mv = mask[(size_t)b * T_LEN + t];
        out[(size_t)b * T_LEN + t] = (s * mv + pb[0]) * mv;
    }
}

extern "C" void kernel_launch(void* const* d_in, const int* in_sizes, int n_in,
                              void* d_out, int out_size, void* d_ws, size_t ws_size,
                              hipStream_t stream)
{
    const float* x    = (const float*)d_in[0];
    const float* nf0  = (const float*)d_in[1];
    const float* xm   = (const float*)d_in[2];
    const float* spk  = (const float*)d_in[3];
    const float* prw  = (const float*)d_in[4];
    const float* prb  = (const float*)d_in[5];
    const float* f0w  = (const float*)d_in[6];
    const float* f0b  = (const float*)d_in[7];
    const float* cw   = (const float*)d_in[8];
    const float* cb   = (const float*)d_in[9];
    const float* pjw  = (const float*)d_in[10];
    const float* pjb  = (const float*)d_in[11];
    const float* qw   = (const float*)d_in[12];
    const float* qb   = (const float*)d_in[13];
    const float* kw   = (const float*)d_in[14];
    const float* kb   = (const float*)d_in[15];
    const float* vw   = (const float*)d_in[16];
    const float* vb   = (const float*)d_in[17];
    const float* ow   = (const float*)d_in[18];
    const float* ob   = (const float*)d_in[19];
    const float* ln0g = (const float*)d_in[20];
    const float* ln0b = (const float*)d_in[21];
    const float* ln1g = (const float*)d_in[22];
    const float* ln1b = (const float*)d_in[23];
    const float* f1w  = (const float*)d_in[24];
    const float* f1b  = (const float*)d_in[25];
    const float* f2w  = (const float*)d_in[26];
    const float* f2b  = (const float*)d_in[27];
    float* out = (float*)d_out;

    const size_t NCT = (size_t)B_SZ * C_CH * T_LEN;
    char* wp = (char*)d_ws;
    float* xbuf = (float*)wp; wp += NCT * 4;                       // residual stream f32
    float* t0   = (float*)wp; wp += NCT * 4;                       // scratch f32
    char* big = wp; wp += (size_t)B_SZ * T_LEN * FC_CH * 2;        // qkv / h1 / xT alias
    float*     xT  = (float*)big;                                  // [b][t][512] f32
    _Float16*  qkv = (_Float16*)big;                               // [b][t][1536] f16
    _Float16*  h1  = (_Float16*)big;                               // [b][t][2048] f16
    char* r2 = wp; wp += (size_t)B_SZ * T_LEN * C_CH * 2;          // obf / spkT alias
    _Float16* obf  = (_Float16*)r2;                                // [b][t][512] f16
    float*    spkT = (float*)r2;                                   // [b][t][256] f32
    _Float16* Wqkv = (_Float16*)wp; wp += (size_t)L_N * 1536 * 512 * 2;
    _Float16* Wo   = (_Float16*)wp; wp += (size_t)L_N * 512 * 512 * 2;
    _Float16* Wcnd = (_Float16*)wp; wp += (size_t)512 * 256 * 2;
    _Float16* Wpre = (_Float16*)wp; wp += (size_t)512 * 512 * 3 * 2;
    _Float16* Wf1  = (_Float16*)wp; wp += (size_t)L_N * 2048 * 512 * 3 * 2;
    _Float16* Wf2  = (_Float16*)wp; wp += (size_t)L_N * 512 * 2048 * 3 * 2;
    float*    Bqkv = (float*)wp;    wp += (size_t)L_N * 1536 * 4;

    dim3 blk(256);
    dim3 gC(16, 4, B_SZ);      // M=512 convs
    dim3 gQ(16, 12, B_SZ);     // M=1536 fused QKV
    dim3 gF(16, 16, B_SZ);     // M=2048 ffn1
    dim3 gAT(16, H_N, B_SZ);   // flash
    dim3 gLN(T_LEN / 4, B_SZ);

    // ---- weight prepack (every call; ws is re-poisoned) ----
    {
        int n;
        n = C_CH * S_CH;            cast_f16<<<(n + 255) / 256, blk, 0, stream>>>(cw, Wcnd, n);
        n = L_N * C_CH * C_CH;      cast_f16<<<(n + 255) / 256, blk, 0, stream>>>(ow, Wo, n);
        n = C_CH * C_CH * 3;        prepack_k3<<<(n + 255) / 256, blk, 0, stream>>>(prw, Wpre, C_CH, n);
        n = L_N * FC_CH * C_CH * 3; prepack_k3<<<(n + 255) / 256, blk, 0, stream>>>(f1w, Wf1, C_CH, n);
        n = L_N * C_CH * FC_CH * 3; prepack_k3<<<(n + 255) / 256, blk, 0, stream>>>(f2w, Wf2, FC_CH, n);
        n = L_N * 1536 * 512;       prepack_qkv<<<(n + 255) / 256, blk, 0, stream>>>(qw, kw, vw, qb, kb, vb, Wqkv, Bqkv);
    }

    // ---- prologue ----
    transpose_f0<<<dim3(64, 16, B_SZ), blk, 0, stream>>>(x, xT, C_CH, nf0, f0w, f0b, 1);
    transpose_f0<<<dim3(64, 8, B_SZ), blk, 0, stream>>>(spk, spkT, S_CH, nullptr, nullptr, nullptr, 0);
    conv_gemm_mfma<1, 0, 0><<<gC, blk, 0, stream>>>(spkT, Wcnd, cb, xT, xm, t0, S_CH, C_CH, 0, 0, 0, 0);
    conv_gemm_mfma<3, 0, 0><<<gC, blk, 0, stream>>>(t0, Wpre, prb, nullptr, xm, xbuf, C_CH, C_CH, 1, 0, 0, 1);

    for (int l = 0; l < L_N; ++l) {
        const size_t bo = (size_t)l * C_CH;
        conv_gemm_mfma<1, 0, 1><<<gQ, blk, 0, stream>>>(xbuf, Wqkv + (size_t)l * 1536 * 512, Bqkv + l * 1536,
                                                        nullptr, xm, qkv, C_CH, 1536, 0, 0, 0, 0);
        flash_attn_mfma<<<gAT, blk, 0, stream>>>(qkv, obf);
        conv_gemm_mfma<1, 1, 0><<<gC, blk, 0, stream>>>(obf, Wo + (size_t)l * 512 * 512, ob + bo,
                                                        nullptr, xm, t0, C_CH, C_CH, 0, 0, 0, 0);
        ln_kernel<<<gLN, blk, 0, stream>>>(xbuf, t0, ln0g + bo, ln0b + bo, xbuf);
        conv_gemm_mfma<3, 0, 1><<<gF, blk, 0, stream>>>(xbuf, Wf1 + (size_t)l * FC_CH * C_CH * 3, f1b + (size_t)l * FC_CH,
                                                        nullptr, xm, h1, C_CH, FC_CH, 2, 1, 1, 0);
        conv_gemm_mfma<3, 1, 0><<<gC, blk, 0, stream>>>(h1, Wf2 + (size_t)l * C_CH * FC_CH * 3, f2b + bo,
                                                        nullptr, xm, t0, FC_CH, C_CH, 2, 0, 1, 1);
        ln_kernel<<<gLN, blk, 0, stream>>>(xbuf, t0, ln1g + bo, ln1b + bo, xbuf);
    }
    proj_kernel<<<gLN, blk, 0, stream>>>(xbuf, pjw, pjb, xm, out);
}

// Round 5
// 2815.337 us; speedup vs baseline: 9.0347x; 1.1577x over previous
//
#include <hip/hip_runtime.h>
#include <cstdint>
#include <cstddef>

#define T_LEN 2048
#define B_SZ 4
#define C_CH 512
#define H_N 8
#define DK_ 64
#define FC_CH 2048
#define L_N 6
#define KW 3
#define S_CH 256

typedef _Float16 h8 __attribute__((ext_vector_type(8)));
typedef _Float16 h4 __attribute__((ext_vector_type(4)));
typedef float floatx4 __attribute__((ext_vector_type(4)));

// ---------------------------------------------------------------------------
// Weight prepack kernels (run every call; weights -> f16 in ws).
// ---------------------------------------------------------------------------
__global__ __launch_bounds__(256)
void cast_f16(const float* __restrict__ src, _Float16* __restrict__ dst, int n)
{
    int i = blockIdx.x * 256 + threadIdx.x;
    if (i < n) dst[i] = (_Float16)src[i];
}

// src [row][c][k] (k fastest, K=3) -> dst [row][c0blk][k][cl] (32-ch chunks)
__global__ __launch_bounds__(256)
void prepack_k3(const float* __restrict__ src, _Float16* __restrict__ dst,
                int Cin, int total)
{
    int i = blockIdx.x * 256 + threadIdx.x;
    if (i >= total) return;
    const int rk = Cin * 3;
    int row = i / rk, o = i - row * rk;
    int blk = o / 96, rr = o - blk * 96;
    int k = rr >> 5, cl = rr & 31;
    dst[i] = (_Float16)src[(size_t)row * rk + (size_t)(blk * 32 + cl) * 3 + k];
}

// concat q|k weights into [l][1024][512] f16 + biases into [l][1024] f32
__global__ __launch_bounds__(256)
void prepack_qk(const float* __restrict__ qw, const float* __restrict__ kw,
                const float* __restrict__ qb, const float* __restrict__ kb,
                _Float16* __restrict__ dst, float* __restrict__ bdst)
{
    int i = blockIdx.x * 256 + threadIdx.x;
    const int total = L_N * 1024 * 512;
    if (i < total) {
        int l = i / (1024 * 512);
        int o = i - l * (1024 * 512);
        int m = o >> 9, c = o & 511;
        const float* s = (m < 512) ? qw : kw;
        dst[i] = (_Float16)s[((size_t)l * 512 + (m & 511)) * 512 + c];
    }
    if (i < L_N * 1024) {
        int l = i / 1024, m = i - l * 1024;
        const float* s = (m < 512) ? qb : kb;
        bdst[i] = s[l * 512 + (m & 511)];
    }
}

// ---------------------------------------------------------------------------
// Transpose [b][Cd][T] -> [b][T][Cd] (f32), optionally fusing the f0 conv add.
// ---------------------------------------------------------------------------
__global__ __launch_bounds__(256)
void transpose_f0(const float* __restrict__ src, float* __restrict__ dst, int Cd,
                  const float* __restrict__ nf0, const float* __restrict__ f0w,
                  const float* __restrict__ f0b, int do_f0)
{
    __shared__ float tile[32][33];
    const int tl = threadIdx.x & 31;
    const int r  = threadIdx.x >> 5;
    const int t00 = blockIdx.x * 32;
    const int c00 = blockIdx.y * 32;
    const int b   = blockIdx.z;
    const float* s0 = src + (size_t)b * Cd * T_LEN;
#pragma unroll
    for (int rr = 0; rr < 4; ++rr) {
        int cl = r + rr * 8;
        tile[cl][tl] = s0[(size_t)(c00 + cl) * T_LEN + t00 + tl];
    }
    __syncthreads();
    float* d0 = dst + (size_t)b * T_LEN * Cd;
    const int cg = c00 + tl;
#pragma unroll
    for (int rr = 0; rr < 4; ++rr) {
        int tlo = r + rr * 8;
        float v = tile[tl][tlo];
        if (do_f0) {
            int tg = t00 + tlo;
            float a = f0b[cg];
#pragma unroll
            for (int k = 0; k < 3; ++k) {
                int gt = tg + k - 1;
                if (gt >= 0 && gt < T_LEN) a += f0w[cg * 3 + k] * nf0[(size_t)b * T_LEN + gt];
            }
            v += a;
        }
        d0[(size_t)(t00 + tlo) * Cd + cg] = v;
    }
}

// ---------------------------------------------------------------------------
// Conv1d-as-GEMM on MFMA, prepacked f16 weights.
// in: [b][T][Cin] (f32/f16 per INF16).
// OUTMODE: 0 = f32 [t][stride], 1 = f16 [t][stride], 2 = f16 transposed [b][m][t].
// KK=1: 64-ch chunks (2 sections, 32 MFMA/barrier); KK=3: 32-ch chunks, 3 taps
// from one halo-staged B tile (48 MFMA/barrier).
// ---------------------------------------------------------------------------
template<int KK, int INF16, int OUTMODE>
__global__ __launch_bounds__(256)
void conv_gemm_mfma(const void* __restrict__ in_v, const _Float16* __restrict__ Wpk,
                    const float* __restrict__ bias, const float* __restrict__ res,
                    const float* __restrict__ mask, void* __restrict__ out_v,
                    int Cin, int out_stride, int pl, int do_relu,
                    int mask_in, int mask_out)
{
    constexpr int CS   = (KK == 3) ? 32 : 64;   // channels per chunk
    constexpr int NSEC = (KK == 3) ? 3 : 2;     // 32-wide A sections per chunk
    constexpr int AST  = NSEC * 32 + 8;         // 104 / 72
    constexpr int HALO = (KK == 3) ? 2 : 0;
    constexpr int RB   = 128 + 2 * HALO;
    constexpr int BST  = CS + 8;                // 40 / 72
    __shared__ _Float16 sA[128 * AST];
    __shared__ _Float16 sB[RB * BST];

    const int tid = threadIdx.x;
    const int lane = tid & 63;
    const int wid = tid >> 6;
    const int wm = wid >> 1, wt = wid & 1;
    const int r = lane & 15, q4 = lane >> 4;
    const int t0 = blockIdx.x * 128;
    const int m0 = blockIdx.y * 128;
    const int b  = blockIdx.z;
    const float* mk = mask + (size_t)b * T_LEN;

    floatx4 acc[4][4];
#pragma unroll
    for (int i = 0; i < 4; ++i)
#pragma unroll
        for (int j = 0; j < 4; ++j)
#pragma unroll
            for (int c = 0; c < 4; ++c) acc[i][j][c] = 0.f;

    for (int c0 = 0; c0 < Cin; c0 += CS) {
        // ---- stage A: straight f16 copies, 2 threads/row ----
        {
            const int row = tid >> 1;
            const int h0 = (tid & 1) * (NSEC * 16);
            const _Float16* src = Wpk + (size_t)(m0 + row) * Cin * KK + (size_t)c0 * KK + h0;
            _Float16* dst = &sA[row * AST + h0];
#pragma unroll
            for (int j = 0; j < NSEC * 2; ++j)
                *reinterpret_cast<h8*>(dst + j * 8) = *reinterpret_cast<const h8*>(src + j * 8);
        }
        // ---- stage B ----
        if (INF16) {
            const _Float16* in_h = (const _Float16*)in_v + (size_t)b * T_LEN * Cin;
            for (int id = tid; id < RB * (CS / 16); id += 256) {
                int row = id / (CS / 16), c16 = (id % (CS / 16)) * 16;
                int gt = t0 + row - HALO;
                h8 v0, v1;
                if (HALO == 0 || (gt >= 0 && gt < T_LEN)) {
                    const _Float16* p = &in_h[(size_t)gt * Cin + c0 + c16];
                    v0 = *reinterpret_cast<const h8*>(p);
                    v1 = *reinterpret_cast<const h8*>(p + 8);
                    if (mask_in) {
                        _Float16 mv = (_Float16)mk[gt];
                        v0 *= mv; v1 *= mv;
                    }
                } else {
#pragma unroll
                    for (int j = 0; j < 8; ++j) { v0[j] = (_Float16)0.f; v1[j] = (_Float16)0.f; }
                }
                *reinterpret_cast<h8*>(&sB[row * BST + c16]) = v0;
                *reinterpret_cast<h8*>(&sB[row * BST + c16 + 8]) = v1;
            }
        } else {
            const float* in_f = (const float*)in_v + (size_t)b * T_LEN * Cin;
            for (int id = tid; id < RB * (CS / 4); id += 256) {
                int row = id / (CS / 4), c4 = (id % (CS / 4)) * 4;
                int gt = t0 + row - HALO;
                h4 hv;
                if (HALO == 0 || (gt >= 0 && gt < T_LEN)) {
                    float4 f = *reinterpret_cast<const float4*>(&in_f[(size_t)gt * Cin + c0 + c4]);
                    if (mask_in) { float mv = mk[gt]; f.x *= mv; f.y *= mv; f.z *= mv; f.w *= mv; }
                    hv[0] = (_Float16)f.x; hv[1] = (_Float16)f.y;
                    hv[2] = (_Float16)f.z; hv[3] = (_Float16)f.w;
                } else {
#pragma unroll
                    for (int j = 0; j < 4; ++j) hv[j] = (_Float16)0.f;
                }
                *reinterpret_cast<h4*>(&sB[row * BST + c4]) = hv;
            }
        }
        __syncthreads();
        // ---- NSEC sections x 16 MFMA ----
#pragma unroll
        for (int sec = 0; sec < NSEC; ++sec) {
            h8 af[4], bf[4];
#pragma unroll
            for (int im = 0; im < 4; ++im)
                af[im] = *reinterpret_cast<const h8*>(&sA[(wm * 64 + im * 16 + r) * AST + sec * 32 + q4 * 8]);
            const int rb0 = (KK == 3) ? (wt * 64 + r + sec - pl + HALO) : (wt * 64 + r);
            const int cb0 = (KK == 3) ? 0 : sec * 32;
#pragma unroll
            for (int jt = 0; jt < 4; ++jt)
                bf[jt] = *reinterpret_cast<const h8*>(&sB[(rb0 + jt * 16) * BST + cb0 + q4 * 8]);
#pragma unroll
            for (int im = 0; im < 4; ++im)
#pragma unroll
                for (int jt = 0; jt < 4; ++jt)
                    acc[im][jt] = __builtin_amdgcn_mfma_f32_16x16x32_f16(af[im], bf[jt], acc[im][jt], 0, 0, 0);
        }
        __syncthreads();
    }
    // ---- epilogue: D row = m (q4*4+reg), col = t (r) ----
#pragma unroll
    for (int im = 0; im < 4; ++im) {
        const int mb = m0 + wm * 64 + im * 16 + q4 * 4;
        const float4 bv = *reinterpret_cast<const float4*>(&bias[mb]);
#pragma unroll
        for (int jt = 0; jt < 4; ++jt) {
            const int t = t0 + wt * 64 + jt * 16 + r;
            float vv[4];
            vv[0] = acc[im][jt][0] + bv.x;
            vv[1] = acc[im][jt][1] + bv.y;
            vv[2] = acc[im][jt][2] + bv.z;
            vv[3] = acc[im][jt][3] + bv.w;
            if (OUTMODE == 0 && res) {
                const float4 rv = *reinterpret_cast<const float4*>(&res[((size_t)b * T_LEN + t) * out_stride + mb]);
                vv[0] += rv.x; vv[1] += rv.y; vv[2] += rv.z; vv[3] += rv.w;
            }
            if (do_relu) {
#pragma unroll
                for (int c = 0; c < 4; ++c) vv[c] = fmaxf(vv[c], 0.f);
            }
            if (mask_out) {
                const float mv = mk[t];
#pragma unroll
                for (int c = 0; c < 4; ++c) vv[c] *= mv;
            }
            if (OUTMODE == 0) {
                *reinterpret_cast<float4*>((float*)out_v + ((size_t)b * T_LEN + t) * out_stride + mb) =
                    make_float4(vv[0], vv[1], vv[2], vv[3]);
            } else if (OUTMODE == 1) {
                h4 hv;
                hv[0] = (_Float16)vv[0]; hv[1] = (_Float16)vv[1];
                hv[2] = (_Float16)vv[2]; hv[3] = (_Float16)vv[3];
                *reinterpret_cast<h4*>((_Float16*)out_v + ((size_t)b * T_LEN + t) * out_stride + mb) = hv;
            } else {
                _Float16* op = (_Float16*)out_v;
#pragma unroll
                for (int reg = 0; reg < 4; ++reg)
                    op[((size_t)b * C_CH + mb + reg) * T_LEN + t] = (_Float16)vv[reg];
            }
        }
    }
}

// ---------------------------------------------------------------------------
// MFMA flash attention with ONLINE softmax (running max: p <= 1, f16-safe —
// round 4's fixed-origin variant overflowed f16 in the P store).
// qk: [b][t][1024] f16 (q|k); vt: [b][h*64+d][t] f16 (pre-transposed by V GEMM);
// o: [b][t][512] f16. Q-tile 128 (32 rows/wave), K-tile 64. blockIdx.x reversed
// so the longest causal blocks dispatch first.
// ---------------------------------------------------------------------------
__global__ __launch_bounds__(256)
void flash_attn_mfma(const _Float16* __restrict__ qk, const _Float16* __restrict__ vt,
                     _Float16* __restrict__ o)
{
    __shared__ _Float16 sK[64 * 72];    // [s][d]
    __shared__ _Float16 sVt[64 * 72];   // [d][s]
    __shared__ _Float16 sP[128 * 72];   // [q][s]
    const int tid = threadIdx.x;
    const int lane = tid & 63;
    const int w = tid >> 6;
    const int r = lane & 15, q4 = lane >> 4;
    const int qt0 = (int)(15 - blockIdx.x) * 128;   // reversed: longest first
    const int h = blockIdx.y, b = blockIdx.z;
    const size_t tb = (size_t)b * T_LEN;
    const int hq = h * 64, hk = 512 + h * 64;
    const _Float16* vbase = vt + ((size_t)b * C_CH + h * 64) * T_LEN;

    // Q fragments, pre-scaled by 1/sqrt(64)=0.125 (exact in f16)
    h8 qf[2][2];
#pragma unroll
    for (int im = 0; im < 2; ++im)
#pragma unroll
        for (int dc = 0; dc < 2; ++dc) {
            h8 t = *reinterpret_cast<const h8*>(
                &qk[(tb + qt0 + w * 32 + im * 16 + r) * 1024 + hq + dc * 32 + q4 * 8]);
            qf[im][dc] = t * (_Float16)0.125f;
        }

    floatx4 oacc[2][4];
    float mrow[2][4], lrow[2][4];
#pragma unroll
    for (int im = 0; im < 2; ++im)
#pragma unroll
        for (int reg = 0; reg < 4; ++reg) {
            mrow[im][reg] = -__builtin_inff();
            lrow[im][reg] = 0.f;
        }
#pragma unroll
    for (int im = 0; im < 2; ++im)
#pragma unroll
        for (int jd = 0; jd < 4; ++jd)
#pragma unroll
            for (int c = 0; c < 4; ++c) oacc[im][jd][c] = 0.f;

    const int qhi = qt0 + w * 32 + 31;
    const int nk = (qt0 >> 6) + 2;
    for (int kt = 0; kt < nk; ++kt) {
        const int kt0 = kt * 64;
        __syncthreads();
        {   // stage K [s][d]
            int row = tid >> 2, c16 = (tid & 3) * 16;
            const _Float16* src = &qk[(tb + kt0 + row) * 1024 + hk + c16];
            *reinterpret_cast<h8*>(&sK[row * 72 + c16]) = *reinterpret_cast<const h8*>(src);
            *reinterpret_cast<h8*>(&sK[row * 72 + c16 + 8]) = *reinterpret_cast<const h8*>(src + 8);
        }
#pragma unroll
        for (int p = 0; p < 2; ++p) {   // stage V^T [d][s] — vectorized, conflict-free
            int id = p * 256 + tid;
            int d = id >> 3, s8 = (id & 7) * 8;
            *reinterpret_cast<h8*>(&sVt[d * 72 + s8]) =
                *reinterpret_cast<const h8*>(&vbase[(size_t)d * T_LEN + kt0 + s8]);
        }
        __syncthreads();
        if (kt0 <= qhi) {
            // ---- S = Q.K^T ----
            floatx4 sacc[2][4];
#pragma unroll
            for (int im = 0; im < 2; ++im)
#pragma unroll
                for (int js = 0; js < 4; ++js)
#pragma unroll
                    for (int c = 0; c < 4; ++c) sacc[im][js][c] = 0.f;
#pragma unroll
            for (int dc = 0; dc < 2; ++dc) {
                h8 kf[4];
#pragma unroll
                for (int js = 0; js < 4; ++js)
                    kf[js] = *reinterpret_cast<const h8*>(&sK[(js * 16 + r) * 72 + dc * 32 + q4 * 8]);
#pragma unroll
                for (int im = 0; im < 2; ++im)
#pragma unroll
                    for (int js = 0; js < 4; ++js)
                        sacc[im][js] = __builtin_amdgcn_mfma_f32_16x16x32_f16(qf[im][dc], kf[js], sacc[im][js], 0, 0, 0);
            }
            // ---- causal mask (rows q4*4+reg, cols js*16+r) ----
#pragma unroll
            for (int im = 0; im < 2; ++im)
#pragma unroll
                for (int js = 0; js < 4; ++js) {
                    const int s_g = kt0 + js * 16 + r;
#pragma unroll
                    for (int reg = 0; reg < 4; ++reg) {
                        const int q_g = qt0 + w * 32 + im * 16 + q4 * 4 + reg;
                        if (s_g > q_g) sacc[im][js][reg] = -1e4f;
                    }
                }
            // ---- online softmax: tile max -> alpha rescale -> p = exp(s-m) <= 1 ----
            float mt[2][4];
#pragma unroll
            for (int im = 0; im < 2; ++im)
#pragma unroll
                for (int reg = 0; reg < 4; ++reg) {
                    float m0v = fmaxf(fmaxf(sacc[im][0][reg], sacc[im][1][reg]),
                                      fmaxf(sacc[im][2][reg], sacc[im][3][reg]));
#pragma unroll
                    for (int off = 1; off < 16; off <<= 1)
                        m0v = fmaxf(m0v, __shfl_xor(m0v, off));
                    mt[im][reg] = m0v;
                }
            float alpha[2][4];
#pragma unroll
            for (int im = 0; im < 2; ++im)
#pragma unroll
                for (int reg = 0; reg < 4; ++reg) {
                    float mn = fmaxf(mrow[im][reg], mt[im][reg]);
                    alpha[im][reg] = __expf(mrow[im][reg] - mn);
                    mrow[im][reg] = mn;
                    float rs = 0.f;
#pragma unroll
                    for (int js = 0; js < 4; ++js) {
                        float p = __expf(sacc[im][js][reg] - mn);
                        sacc[im][js][reg] = p;
                        rs += p;
                    }
#pragma unroll
                    for (int off = 1; off < 16; off <<= 1)
                        rs += __shfl_xor(rs, off);
                    lrow[im][reg] = lrow[im][reg] * alpha[im][reg] + rs;
                }
#pragma unroll
            for (int im = 0; im < 2; ++im)
#pragma unroll
                for (int jd = 0; jd < 4; ++jd)
#pragma unroll
                    for (int reg = 0; reg < 4; ++reg)
                        oacc[im][jd][reg] *= alpha[im][reg];
            // ---- P -> LDS (per-wave region; p in [0,1], f16-safe) ----
#pragma unroll
            for (int im = 0; im < 2; ++im)
#pragma unroll
                for (int js = 0; js < 4; ++js)
#pragma unroll
                    for (int reg = 0; reg < 4; ++reg)
                        sP[(w * 32 + im * 16 + q4 * 4 + reg) * 72 + js * 16 + r] =
                            (_Float16)sacc[im][js][reg];
            // ---- O += P.V ----
#pragma unroll
            for (int sc = 0; sc < 2; ++sc) {
                h8 pf[2], vf[4];
#pragma unroll
                for (int im = 0; im < 2; ++im)
                    pf[im] = *reinterpret_cast<const h8*>(&sP[(w * 32 + im * 16 + r) * 72 + sc * 32 + q4 * 8]);
#pragma unroll
                for (int jd = 0; jd < 4; ++jd)
                    vf[jd] = *reinterpret_cast<const h8*>(&sVt[(jd * 16 + r) * 72 + sc * 32 + q4 * 8]);
#pragma unroll
                for (int im = 0; im < 2; ++im)
#pragma unroll
                    for (int jd = 0; jd < 4; ++jd)
                        oacc[im][jd] = __builtin_amdgcn_mfma_f32_16x16x32_f16(pf[im], vf[jd], oacc[im][jd], 0, 0, 0);
            }
        }
    }
    // ---- normalize + store (f16) ----
#pragma unroll
    for (int im = 0; im < 2; ++im)
#pragma unroll
        for (int reg = 0; reg < 4; ++reg) {
            const float inv = 1.f / lrow[im][reg];
            const size_t rowb = (tb + qt0 + w * 32 + im * 16 + q4 * 4 + reg) * 512 + h * 64 + r;
#pragma unroll
            for (int jd = 0; jd < 4; ++jd)
                o[rowb + jd * 16] = (_Float16)(oacc[im][jd][reg] * inv);
        }
}

// ---------------------------------------------------------------------------
// Channel LayerNorm on f16 [b][t][512]: one wave per t-row. outx = LN(x+y)*g+be
// ---------------------------------------------------------------------------
__global__ __launch_bounds__(256)
void ln_kernel(const _Float16* __restrict__ x, const _Float16* __restrict__ y,
               const float* __restrict__ g, const float* __restrict__ be,
               _Float16* __restrict__ outx)
{
    const int w = threadIdx.x >> 6, lane = threadIdx.x & 63;
    const int t = blockIdx.x * 4 + w, b = blockIdx.y;
    const size_t base = ((size_t)b * T_LEN + t) * C_CH + lane * 8;
    h8 xv = *reinterpret_cast<const h8*>(&x[base]);
    h8 yv = *reinterpret_cast<const h8*>(&y[base]);
    float v[8];
#pragma unroll
    for (int i = 0; i < 8; ++i) v[i] = (float)xv[i] + (float)yv[i];
    float s = 0.f, s2 = 0.f;
#pragma unroll
    for (int i = 0; i < 8; ++i) { s += v[i]; s2 += v[i] * v[i]; }
#pragma unroll
    for (int off = 1; off < 64; off <<= 1) {
        s  += __shfl_xor(s, off);
        s2 += __shfl_xor(s2, off);
    }
    const float mean = s * (1.f / C_CH);
    const float var  = s2 * (1.f / C_CH) - mean * mean;
    const float rstd = rsqrtf(var + 1e-5f);
    float4 g0 = *reinterpret_cast<const float4*>(&g[lane * 8]);
    float4 g1 = *reinterpret_cast<const float4*>(&g[lane * 8 + 4]);
    float4 b0 = *reinterpret_cast<const float4*>(&be[lane * 8]);
    float4 b1 = *reinterpret_cast<const float4*>(&be[lane * 8 + 4]);
    const float gg[8] = {g0.x, g0.y, g0.z, g0.w, g1.x, g1.y, g1.z, g1.w};
    const float bb[8] = {b0.x, b0.y, b0.z, b0.w, b1.x, b1.y, b1.z, b1.w};
    h8 ov;
#pragma unroll
    for (int i = 0; i < 8; ++i)
        ov[i] = (_Float16)((v[i] - mean) * rstd * gg[i] + bb[i]);
    *reinterpret_cast<h8*>(&outx[base]) = ov;
}

// out[b,t] = ( mask * sum_c pw[c]*x[b,t,c] + pb ) * mask   (one wave per t)
__global__ __launch_bounds__(256)
void proj_kernel(const _Float16* __restrict__ x, const float* __restrict__ pw,
                 const float* __restrict__ pb, const float* __restrict__ mask,
                 float* __restrict__ out)
{
    const int w = threadIdx.x >> 6, lane = threadIdx.x & 63;
    const int t = blockIdx.x * 4 + w, b = blockIdx.y;
    const size_t base = ((size_t)b * T_LEN + t) * C_CH + lane * 8;
    h8 xv = *reinterpret_cast<const h8*>(&x[base]);
    float4 p0 = *reinterpret_cast<const float4*>(&pw[lane * 8]);
    float4 p1 = *reinterpret_cast<const float4*>(&pw[lane * 8 + 4]);
    const float pp[8] = {p0.x, p0.y, p0.z, p0.w, p1.x, p1.y, p1.z, p1.w};
    float s = 0.f;
#pragma unroll
    for (int i = 0; i < 8; ++i) s += (float)xv[i] * pp[i];
#pragma unroll
    for (int off = 1; off < 64; off <<= 1) s += __shfl_xor(s, off);
    if (lane == 0) {
        const float mv = mask[(size_t)b * T_LEN + t];
        out[(size_t)b * T_LEN + t] = (s * mv + pb[0]) * mv;
    }
}

extern "C" void kernel_launch(void* const* d_in, const int* in_sizes, int n_in,
                              void* d_out, int out_size, void* d_ws, size_t ws_size,
                              hipStream_t stream)
{
    const float* x    = (const float*)d_in[0];
    const float* nf0  = (const float*)d_in[1];
    const float* xm   = (const float*)d_in[2];
    const float* spk  = (const float*)d_in[3];
    const float* prw  = (const float*)d_in[4];
    const float* prb  = (const float*)d_in[5];
    const float* f0w  = (const float*)d_in[6];
    const float* f0b  = (const float*)d_in[7];
    const float* cw   = (const float*)d_in[8];
    const float* cb   = (const float*)d_in[9];
    const float* pjw  = (const float*)d_in[10];
    const float* pjb  = (const float*)d_in[11];
    const float* qw   = (const float*)d_in[12];
    const float* qb   = (const float*)d_in[13];
    const float* kw   = (const float*)d_in[14];
    const float* kb   = (const float*)d_in[15];
    const float* vw   = (const float*)d_in[16];
    const float* vb   = (const float*)d_in[17];
    const float* ow   = (const float*)d_in[18];
    const float* ob   = (const float*)d_in[19];
    const float* ln0g = (const float*)d_in[20];
    const float* ln0b = (const float*)d_in[21];
    const float* ln1g = (const float*)d_in[22];
    const float* ln1b = (const float*)d_in[23];
    const float* f1w  = (const float*)d_in[24];
    const float* f1b  = (const float*)d_in[25];
    const float* f2w  = (const float*)d_in[26];
    const float* f2b  = (const float*)d_in[27];
    float* out = (float*)d_out;

    const size_t NCT = (size_t)B_SZ * C_CH * T_LEN;   // 4.19M elems
    char* wp = (char*)d_ws;
    _Float16* xbuf = (_Float16*)wp; wp += NCT * 2;            // [b][t][512] residual
    _Float16* t0h  = (_Float16*)wp; wp += NCT * 2;            // [b][t][512] sublayer out
    _Float16* qk   = (_Float16*)wp; wp += NCT * 4;            // [b][t][1024]
    _Float16* vt   = (_Float16*)wp; wp += NCT * 2;            // [b][h*64+d][t]
    _Float16* obf  = (_Float16*)wp; wp += NCT * 2;            // [b][t][512]
    _Float16* h1   = (_Float16*)wp; wp += NCT * 8;            // [b][t][2048]
    // prologue f32 aliases (dead before their f16 owners are written)
    float* xT   = (float*)h1;     // [b][t][512] f32
    float* t0f  = (float*)qk;     // [b][t][512] f32
    float* spkT = (float*)vt;     // [b][t][256] f32
    _Float16* Wqk  = (_Float16*)wp; wp += (size_t)L_N * 1024 * 512 * 2;
    _Float16* Wv   = (_Float16*)wp; wp += (size_t)L_N * 512 * 512 * 2;
    _Float16* Wo   = (_Float16*)wp; wp += (size_t)L_N * 512 * 512 * 2;
    _Float16* Wcnd = (_Float16*)wp; wp += (size_t)512 * 256 * 2;
    _Float16* Wpre = (_Float16*)wp; wp += (size_t)512 * 512 * 3 * 2;
    _Float16* Wf1  = (_Float16*)wp; wp += (size_t)L_N * 2048 * 512 * 3 * 2;
    _Float16* Wf2  = (_Float16*)wp; wp += (size_t)L_N * 512 * 2048 * 3 * 2;
    float*    Bqk  = (float*)wp;    wp += (size_t)L_N * 1024 * 4;

    dim3 blk(256);
    dim3 gC(16, 4, B_SZ);      // M=512 convs
    dim3 gQK(16, 8, B_SZ);     // M=1024 fused QK
    dim3 gF(16, 16, B_SZ);     // M=2048 ffn1
    dim3 gAT(16, H_N, B_SZ);   // flash
    dim3 gLN(T_LEN / 4, B_SZ);

    // ---- weight prepack ----
    {
        int n;
        n = C_CH * S_CH;            cast_f16<<<(n + 255) / 256, blk, 0, stream>>>(cw, Wcnd, n);
        n = L_N * C_CH * C_CH;      cast_f16<<<(n + 255) / 256, blk, 0, stream>>>(ow, Wo, n);
        n = L_N * C_CH * C_CH;      cast_f16<<<(n + 255) / 256, blk, 0, stream>>>(vw, Wv, n);
        n = C_CH * C_CH * 3;        prepack_k3<<<(n + 255) / 256, blk, 0, stream>>>(prw, Wpre, C_CH, n);
        n = L_N * FC_CH * C_CH * 3; prepack_k3<<<(n + 255) / 256, blk, 0, stream>>>(f1w, Wf1, C_CH, n);
        n = L_N * C_CH * FC_CH * 3; prepack_k3<<<(n + 255) / 256, blk, 0, stream>>>(f2w, Wf2, FC_CH, n);
        n = L_N * 1024 * 512;       prepack_qk<<<(n + 255) / 256, blk, 0, stream>>>(qw, kw, qb, kb, Wqk, Bqk);
    }

    // ---- prologue ----
    transpose_f0<<<dim3(64, 16, B_SZ), blk, 0, stream>>>(x, xT, C_CH, nf0, f0w, f0b, 1);
    transpose_f0<<<dim3(64, 8, B_SZ), blk, 0, stream>>>(spk, spkT, S_CH, nullptr, nullptr, nullptr, 0);
    conv_gemm_mfma<1, 0, 0><<<gC, blk, 0, stream>>>(spkT, Wcnd, cb, xT, xm, t0f, S_CH, C_CH, 0, 0, 0, 0);
    conv_gemm_mfma<3, 0, 1><<<gC, blk, 0, stream>>>(t0f, Wpre, prb, nullptr, xm, xbuf, C_CH, C_CH, 1, 0, 0, 1);

    for (int l = 0; l < L_N; ++l) {
        const size_t bo = (size_t)l * C_CH;
        conv_gemm_mfma<1, 1, 1><<<gQK, blk, 0, stream>>>(xbuf, Wqk + (size_t)l * 1024 * 512, Bqk + l * 1024,
                                                         nullptr, xm, qk, C_CH, 1024, 0, 0, 0, 0);
        conv_gemm_mfma<1, 1, 2><<<gC, blk, 0, stream>>>(xbuf, Wv + (size_t)l * 512 * 512, vb + bo,
                                                        nullptr, xm, vt, C_CH, 0, 0, 0, 0, 0);
        flash_attn_mfma<<<gAT, blk, 0, stream>>>(qk, vt, obf);
        conv_gemm_mfma<1, 1, 1><<<gC, blk, 0, stream>>>(obf, Wo + (size_t)l * 512 * 512, ob + bo,
                                                        nullptr, xm, t0h, C_CH, C_CH, 0, 0, 0, 0);
        ln_kernel<<<gLN, blk, 0, stream>>>(xbuf, t0h, ln0g + bo, ln0b + bo, xbuf);
        conv_gemm_mfma<3, 1, 1><<<gF, blk, 0, stream>>>(xbuf, Wf1 + (size_t)l * FC_CH * C_CH * 3, f1b + (size_t)l * FC_CH,
                                                        nullptr, xm, h1, C_CH, FC_CH, 2, 1, 1, 0);
        conv_gemm_mfma<3, 1, 1><<<gC, blk, 0, stream>>>(h1, Wf2 + (size_t)l * C_CH * FC_CH * 3, f2b + bo,
                                                        nullptr, xm, t0h, FC_CH, C_CH, 2, 0, 1, 1);
        ln_kernel<<<gLN, blk, 0, stream>>>(xbuf, t0h, ln1g + bo, ln1b + bo, xbuf);
    }
    proj_kernel<<<gLN, blk, 0, stream>>>(xbuf, pjw, pjb, xm, out);
}

// Round 6
// 2571.800 us; speedup vs baseline: 9.8903x; 1.0947x over previous
//
#include <hip/hip_runtime.h>
#include <cstdint>
#include <cstddef>

#define T_LEN 2048
#define B_SZ 4
#define C_CH 512
#define H_N 8
#define DK_ 64
#define FC_CH 2048
#define L_N 6
#define KW 3
#define S_CH 256

typedef _Float16 h8 __attribute__((ext_vector_type(8)));
typedef _Float16 h4 __attribute__((ext_vector_type(4)));
typedef float floatx4 __attribute__((ext_vector_type(4)));

// ---------------------------------------------------------------------------
// Weight prepack kernels (run every call; weights -> f16 in ws).
// ---------------------------------------------------------------------------
__global__ __launch_bounds__(256)
void cast_f16(const float* __restrict__ src, _Float16* __restrict__ dst, int n)
{
    int i = blockIdx.x * 256 + threadIdx.x;
    if (i < n) dst[i] = (_Float16)src[i];
}

// src [row][c][k] (k fastest, K=3) -> dst [row][c0blk][k][cl] (32-ch chunks)
__global__ __launch_bounds__(256)
void prepack_k3(const float* __restrict__ src, _Float16* __restrict__ dst,
                int Cin, int total)
{
    int i = blockIdx.x * 256 + threadIdx.x;
    if (i >= total) return;
    const int rk = Cin * 3;
    int row = i / rk, o = i - row * rk;
    int blk = o / 96, rr = o - blk * 96;
    int k = rr >> 5, cl = rr & 31;
    dst[i] = (_Float16)src[(size_t)row * rk + (size_t)(blk * 32 + cl) * 3 + k];
}

// concat q|k|v weights into [l][1536][512] f16 + biases into [l][1536] f32
__global__ __launch_bounds__(256)
void prepack_qkv(const float* __restrict__ qw, const float* __restrict__ kw,
                 const float* __restrict__ vw, const float* __restrict__ qb,
                 const float* __restrict__ kb, const float* __restrict__ vb,
                 _Float16* __restrict__ dst, float* __restrict__ bdst)
{
    int i = blockIdx.x * 256 + threadIdx.x;
    const int total = L_N * 1536 * 512;
    if (i < total) {
        int l = i / (1536 * 512);
        int o = i - l * (1536 * 512);
        int m = o >> 9, c = o & 511;
        const float* s = (m < 512) ? qw : ((m < 1024) ? kw : vw);
        dst[i] = (_Float16)s[((size_t)l * 512 + (m & 511)) * 512 + c];
    }
    if (i < L_N * 1536) {
        int l = i / 1536, m = i - l * 1536;
        const float* s = (m < 512) ? qb : ((m < 1024) ? kb : vb);
        bdst[i] = s[l * 512 + (m & 511)];
    }
}

// ---------------------------------------------------------------------------
// Transpose [b][Cd][T] -> f16 [b][T][Cd], optionally fusing the f0 conv add.
// ---------------------------------------------------------------------------
__global__ __launch_bounds__(256)
void transpose_f0(const float* __restrict__ src, _Float16* __restrict__ dst, int Cd,
                  const float* __restrict__ nf0, const float* __restrict__ f0w,
                  const float* __restrict__ f0b, int do_f0)
{
    __shared__ float tile[32][33];
    const int tl = threadIdx.x & 31;
    const int r  = threadIdx.x >> 5;
    const int t00 = blockIdx.x * 32;
    const int c00 = blockIdx.y * 32;
    const int b   = blockIdx.z;
    const float* s0 = src + (size_t)b * Cd * T_LEN;
#pragma unroll
    for (int rr = 0; rr < 4; ++rr) {
        int cl = r + rr * 8;
        tile[cl][tl] = s0[(size_t)(c00 + cl) * T_LEN + t00 + tl];
    }
    __syncthreads();
    _Float16* d0 = dst + (size_t)b * T_LEN * Cd;
    const int cg = c00 + tl;
#pragma unroll
    for (int rr = 0; rr < 4; ++rr) {
        int tlo = r + rr * 8;
        float v = tile[tl][tlo];
        if (do_f0) {
            int tg = t00 + tlo;
            float a = f0b[cg];
#pragma unroll
            for (int k = 0; k < 3; ++k) {
                int gt = tg + k - 1;
                if (gt >= 0 && gt < T_LEN) a += f0w[cg * 3 + k] * nf0[(size_t)b * T_LEN + gt];
            }
            v += a;
        }
        d0[(size_t)(t00 + tlo) * Cd + cg] = (_Float16)v;
    }
}

// ---------------------------------------------------------------------------
// Conv1d-as-GEMM on MFMA, prepacked f16 weights, f16 activations, SOFTWARE-
// PIPELINED: chunk c+1's global loads (weights + activations) are issued into
// registers during chunk c's MFMAs — required because several dispatches run
// at 1 block/CU where no sibling-wave overlap exists.
// OUTMODE: 1 = f16 [b][t][out_stride] (+res); 3 = fused QKV (m0<1024 -> out_v
// stride 1024; m0>=1024 -> out2 transposed [b][m-1024][t]).
// ---------------------------------------------------------------------------
template<int KK, int OUTMODE>
__global__ __launch_bounds__(256)
void conv_gemm_mfma(const _Float16* __restrict__ in, const _Float16* __restrict__ Wpk,
                    const float* __restrict__ bias, const _Float16* __restrict__ res,
                    const float* __restrict__ mask, _Float16* __restrict__ out_v,
                    _Float16* __restrict__ out2,
                    int Cin, int out_stride, int pl, int do_relu,
                    int mask_in, int mask_out)
{
    constexpr int CS   = (KK == 3) ? 32 : 64;   // channels per chunk
    constexpr int NSEC = (KK == 3) ? 3 : 2;     // 32-wide A sections
    constexpr int AST  = NSEC * 32 + 8;         // 104 / 72
    constexpr int HALO = (KK == 3) ? 2 : 0;
    constexpr int RB   = 128 + 2 * HALO;
    constexpr int BST  = CS + 8;                // 40 / 72
    constexpr int NAH  = NSEC * 2;              // A h8-regs per thread (6 / 4)
    constexpr int NTASK = RB * (CS / 16);       // B 16-half tasks (264 / 512)
    __shared__ _Float16 sA[128 * AST];
    __shared__ _Float16 sB[RB * BST];

    const int tid = threadIdx.x;
    const int lane = tid & 63;
    const int wid = tid >> 6;
    const int wm = wid >> 1, wt = wid & 1;
    const int r = lane & 15, q4 = lane >> 4;
    const int t0 = blockIdx.x * 128;
    const int m0 = blockIdx.y * 128;
    const int b  = blockIdx.z;
    const float* mk = mask + (size_t)b * T_LEN;

    floatx4 acc[4][4];
#pragma unroll
    for (int i = 0; i < 4; ++i)
#pragma unroll
        for (int j = 0; j < 4; ++j)
#pragma unroll
            for (int c = 0; c < 4; ++c) acc[i][j][c] = 0.f;

    // ---- prefetch state (chunk-invariant decode) ----
    const int arow = tid >> 1;
    const int ah0 = (tid & 1) * (NSEC * 16);
    const _Float16* ap = Wpk + (size_t)(m0 + arow) * Cin * KK + ah0;

    int brw[2], bcc[2];
    bool bex[2], bval[2];
    _Float16 bm[2];
    const _Float16* bp[2];
    h8 areg[NAH], breg[2][2];
#pragma unroll
    for (int t2 = 0; t2 < 2; ++t2) {
        const int id = tid + t2 * 256;
        bex[t2] = (id < NTASK);
        const int row = id / (CS / 16);
        const int c16 = (id % (CS / 16)) * 16;
        const int gt = t0 + row - HALO;
        bval[t2] = bex[t2] && gt >= 0 && gt < T_LEN;
        brw[t2] = row; bcc[t2] = c16;
        bm[t2] = (_Float16)((bval[t2] && mask_in) ? mk[gt] : 1.f);
        bp[t2] = in + (size_t)b * T_LEN * Cin + (size_t)gt * Cin + c16;
#pragma unroll
        for (int j = 0; j < 8; ++j) { breg[t2][0][j] = (_Float16)0.f; breg[t2][1][j] = (_Float16)0.f; }
    }
    // prefetch chunk 0
#pragma unroll
    for (int j = 0; j < NAH; ++j) areg[j] = *reinterpret_cast<const h8*>(ap + j * 8);
#pragma unroll
    for (int t2 = 0; t2 < 2; ++t2)
        if (bval[t2]) {
            breg[t2][0] = *reinterpret_cast<const h8*>(bp[t2]);
            breg[t2][1] = *reinterpret_cast<const h8*>(bp[t2] + 8);
        }

    for (int c0 = 0; c0 < Cin; c0 += CS) {
        __syncthreads();                     // LDS consumers of chunk c-1 done
        // ---- regs -> LDS ----
#pragma unroll
        for (int j = 0; j < NAH; ++j)
            *reinterpret_cast<h8*>(&sA[arow * AST + ah0 + j * 8]) = areg[j];
#pragma unroll
        for (int t2 = 0; t2 < 2; ++t2)
            if (bex[t2]) {
                *reinterpret_cast<h8*>(&sB[brw[t2] * BST + bcc[t2]]) = breg[t2][0] * bm[t2];
                *reinterpret_cast<h8*>(&sB[brw[t2] * BST + bcc[t2] + 8]) = breg[t2][1] * bm[t2];
            }
        __syncthreads();
        // ---- issue chunk c+1 global loads (overlap with MFMAs below) ----
        if (c0 + CS < Cin) {
            ap += CS * KK;
#pragma unroll
            for (int j = 0; j < NAH; ++j) areg[j] = *reinterpret_cast<const h8*>(ap + j * 8);
#pragma unroll
            for (int t2 = 0; t2 < 2; ++t2)
                if (bval[t2]) {
                    bp[t2] += CS;
                    breg[t2][0] = *reinterpret_cast<const h8*>(bp[t2]);
                    breg[t2][1] = *reinterpret_cast<const h8*>(bp[t2] + 8);
                }
        }
        // ---- NSEC sections x 16 MFMA ----
#pragma unroll
        for (int sec = 0; sec < NSEC; ++sec) {
            h8 af[4], bf[4];
#pragma unroll
            for (int im = 0; im < 4; ++im)
                af[im] = *reinterpret_cast<const h8*>(&sA[(wm * 64 + im * 16 + r) * AST + sec * 32 + q4 * 8]);
            const int rb0 = (KK == 3) ? (wt * 64 + r + sec - pl + HALO) : (wt * 64 + r);
            const int cb0 = (KK == 3) ? 0 : sec * 32;
#pragma unroll
            for (int jt = 0; jt < 4; ++jt)
                bf[jt] = *reinterpret_cast<const h8*>(&sB[(rb0 + jt * 16) * BST + cb0 + q4 * 8]);
#pragma unroll
            for (int im = 0; im < 4; ++im)
#pragma unroll
                for (int jt = 0; jt < 4; ++jt)
                    acc[im][jt] = __builtin_amdgcn_mfma_f32_16x16x32_f16(af[im], bf[jt], acc[im][jt], 0, 0, 0);
        }
    }
    // ---- epilogue: D row = m (q4*4+reg), col = t (r) ----
#pragma unroll
    for (int im = 0; im < 4; ++im) {
        const int mb = m0 + wm * 64 + im * 16 + q4 * 4;
        const float4 bv = *reinterpret_cast<const float4*>(&bias[mb]);
#pragma unroll
        for (int jt = 0; jt < 4; ++jt) {
            const int t = t0 + wt * 64 + jt * 16 + r;
            float vv[4];
            vv[0] = acc[im][jt][0] + bv.x;
            vv[1] = acc[im][jt][1] + bv.y;
            vv[2] = acc[im][jt][2] + bv.z;
            vv[3] = acc[im][jt][3] + bv.w;
            if (do_relu) {
#pragma unroll
                for (int c = 0; c < 4; ++c) vv[c] = fmaxf(vv[c], 0.f);
            }
            if (mask_out) {
                const float mv = mk[t];
#pragma unroll
                for (int c = 0; c < 4; ++c) vv[c] *= mv;
            }
            if (OUTMODE == 1) {
                const size_t ob = ((size_t)b * T_LEN + t) * out_stride + mb;
                if (res) {
                    const h4 rv = *reinterpret_cast<const h4*>(&res[ob]);
#pragma unroll
                    for (int c = 0; c < 4; ++c) vv[c] += (float)rv[c];
                }
                h4 hv;
#pragma unroll
                for (int c = 0; c < 4; ++c) hv[c] = (_Float16)vv[c];
                *reinterpret_cast<h4*>(&out_v[ob]) = hv;
            } else {   // fused QKV
                if (m0 < 1024) {
                    const size_t ob = ((size_t)b * T_LEN + t) * 1024 + mb;
                    h4 hv;
#pragma unroll
                    for (int c = 0; c < 4; ++c) hv[c] = (_Float16)vv[c];
                    *reinterpret_cast<h4*>(&out_v[ob]) = hv;
                } else {
#pragma unroll
                    for (int reg = 0; reg < 4; ++reg)
                        out2[((size_t)b * C_CH + (mb - 1024) + reg) * T_LEN + t] = (_Float16)vv[reg];
                }
            }
        }
    }
}

// ---------------------------------------------------------------------------
// MFMA flash attention with ONLINE softmax (p <= 1, f16-safe).
// qk: [b][t][1024] f16 (q|k); vt: [b][h*64+d][t] f16; o: [b][t][512] f16.
// Q-tile 128 (32 rows/wave), K-tile 64. blockIdx.x reversed: longest first.
// ---------------------------------------------------------------------------
__global__ __launch_bounds__(256)
void flash_attn_mfma(const _Float16* __restrict__ qk, const _Float16* __restrict__ vt,
                     _Float16* __restrict__ o)
{
    __shared__ _Float16 sK[64 * 72];    // [s][d]
    __shared__ _Float16 sVt[64 * 72];   // [d][s]
    __shared__ _Float16 sP[128 * 72];   // [q][s]
    const int tid = threadIdx.x;
    const int lane = tid & 63;
    const int w = tid >> 6;
    const int r = lane & 15, q4 = lane >> 4;
    const int qt0 = (int)(15 - blockIdx.x) * 128;
    const int h = blockIdx.y, b = blockIdx.z;
    const size_t tb = (size_t)b * T_LEN;
    const int hq = h * 64, hk = 512 + h * 64;
    const _Float16* vbase = vt + ((size_t)b * C_CH + h * 64) * T_LEN;

    h8 qf[2][2];
#pragma unroll
    for (int im = 0; im < 2; ++im)
#pragma unroll
        for (int dc = 0; dc < 2; ++dc) {
            h8 t = *reinterpret_cast<const h8*>(
                &qk[(tb + qt0 + w * 32 + im * 16 + r) * 1024 + hq + dc * 32 + q4 * 8]);
            qf[im][dc] = t * (_Float16)0.125f;
        }

    floatx4 oacc[2][4];
    float mrow[2][4], lrow[2][4];
#pragma unroll
    for (int im = 0; im < 2; ++im)
#pragma unroll
        for (int reg = 0; reg < 4; ++reg) {
            mrow[im][reg] = -__builtin_inff();
            lrow[im][reg] = 0.f;
        }
#pragma unroll
    for (int im = 0; im < 2; ++im)
#pragma unroll
        for (int jd = 0; jd < 4; ++jd)
#pragma unroll
            for (int c = 0; c < 4; ++c) oacc[im][jd][c] = 0.f;

    const int qhi = qt0 + w * 32 + 31;
    const int nk = (qt0 >> 6) + 2;
    for (int kt = 0; kt < nk; ++kt) {
        const int kt0 = kt * 64;
        __syncthreads();
        {
            int row = tid >> 2, c16 = (tid & 3) * 16;
            const _Float16* src = &qk[(tb + kt0 + row) * 1024 + hk + c16];
            *reinterpret_cast<h8*>(&sK[row * 72 + c16]) = *reinterpret_cast<const h8*>(src);
            *reinterpret_cast<h8*>(&sK[row * 72 + c16 + 8]) = *reinterpret_cast<const h8*>(src + 8);
        }
#pragma unroll
        for (int p = 0; p < 2; ++p) {
            int id = p * 256 + tid;
            int d = id >> 3, s8 = (id & 7) * 8;
            *reinterpret_cast<h8*>(&sVt[d * 72 + s8]) =
                *reinterpret_cast<const h8*>(&vbase[(size_t)d * T_LEN + kt0 + s8]);
        }
        __syncthreads();
        if (kt0 <= qhi) {
            floatx4 sacc[2][4];
#pragma unroll
            for (int im = 0; im < 2; ++im)
#pragma unroll
                for (int js = 0; js < 4; ++js)
#pragma unroll
                    for (int c = 0; c < 4; ++c) sacc[im][js][c] = 0.f;
#pragma unroll
            for (int dc = 0; dc < 2; ++dc) {
                h8 kf[4];
#pragma unroll
                for (int js = 0; js < 4; ++js)
                    kf[js] = *reinterpret_cast<const h8*>(&sK[(js * 16 + r) * 72 + dc * 32 + q4 * 8]);
#pragma unroll
                for (int im = 0; im < 2; ++im)
#pragma unroll
                    for (int js = 0; js < 4; ++js)
                        sacc[im][js] = __builtin_amdgcn_mfma_f32_16x16x32_f16(qf[im][dc], kf[js], sacc[im][js], 0, 0, 0);
            }
#pragma unroll
            for (int im = 0; im < 2; ++im)
#pragma unroll
                for (int js = 0; js < 4; ++js) {
                    const int s_g = kt0 + js * 16 + r;
#pragma unroll
                    for (int reg = 0; reg < 4; ++reg) {
                        const int q_g = qt0 + w * 32 + im * 16 + q4 * 4 + reg;
                        if (s_g > q_g) sacc[im][js][reg] = -1e4f;
                    }
                }
            float mt[2][4];
#pragma unroll
            for (int im = 0; im < 2; ++im)
#pragma unroll
                for (int reg = 0; reg < 4; ++reg) {
                    float m0v = fmaxf(fmaxf(sacc[im][0][reg], sacc[im][1][reg]),
                                      fmaxf(sacc[im][2][reg], sacc[im][3][reg]));
#pragma unroll
                    for (int off = 1; off < 16; off <<= 1)
                        m0v = fmaxf(m0v, __shfl_xor(m0v, off));
                    mt[im][reg] = m0v;
                }
            float alpha[2][4];
#pragma unroll
            for (int im = 0; im < 2; ++im)
#pragma unroll
                for (int reg = 0; reg < 4; ++reg) {
                    float mn = fmaxf(mrow[im][reg], mt[im][reg]);
                    alpha[im][reg] = __expf(mrow[im][reg] - mn);
                    mrow[im][reg] = mn;
                    float rs = 0.f;
#pragma unroll
                    for (int js = 0; js < 4; ++js) {
                        float p = __expf(sacc[im][js][reg] - mn);
                        sacc[im][js][reg] = p;
                        rs += p;
                    }
#pragma unroll
                    for (int off = 1; off < 16; off <<= 1)
                        rs += __shfl_xor(rs, off);
                    lrow[im][reg] = lrow[im][reg] * alpha[im][reg] + rs;
                }
#pragma unroll
            for (int im = 0; im < 2; ++im)
#pragma unroll
                for (int jd = 0; jd < 4; ++jd)
#pragma unroll
                    for (int reg = 0; reg < 4; ++reg)
                        oacc[im][jd][reg] *= alpha[im][reg];
#pragma unroll
            for (int im = 0; im < 2; ++im)
#pragma unroll
                for (int js = 0; js < 4; ++js)
#pragma unroll
                    for (int reg = 0; reg < 4; ++reg)
                        sP[(w * 32 + im * 16 + q4 * 4 + reg) * 72 + js * 16 + r] =
                            (_Float16)sacc[im][js][reg];
#pragma unroll
            for (int sc = 0; sc < 2; ++sc) {
                h8 pf[2], vf[4];
#pragma unroll
                for (int im = 0; im < 2; ++im)
                    pf[im] = *reinterpret_cast<const h8*>(&sP[(w * 32 + im * 16 + r) * 72 + sc * 32 + q4 * 8]);
#pragma unroll
                for (int jd = 0; jd < 4; ++jd)
                    vf[jd] = *reinterpret_cast<const h8*>(&sVt[(jd * 16 + r) * 72 + sc * 32 + q4 * 8]);
#pragma unroll
                for (int im = 0; im < 2; ++im)
#pragma unroll
                    for (int jd = 0; jd < 4; ++jd)
                        oacc[im][jd] = __builtin_amdgcn_mfma_f32_16x16x32_f16(pf[im], vf[jd], oacc[im][jd], 0, 0, 0);
            }
        }
    }
#pragma unroll
    for (int im = 0; im < 2; ++im)
#pragma unroll
        for (int reg = 0; reg < 4; ++reg) {
            const float inv = 1.f / lrow[im][reg];
            const size_t rowb = (tb + qt0 + w * 32 + im * 16 + q4 * 4 + reg) * 512 + h * 64 + r;
#pragma unroll
            for (int jd = 0; jd < 4; ++jd)
                o[rowb + jd * 16] = (_Float16)(oacc[im][jd][reg] * inv);
        }
}

// ---------------------------------------------------------------------------
// Channel LayerNorm on f16 [b][t][512]: one wave per t-row. outx = LN(x+y)*g+be
// ---------------------------------------------------------------------------
__global__ __launch_bounds__(256)
void ln_kernel(const _Float16* __restrict__ x, const _Float16* __restrict__ y,
               const float* __restrict__ g, const float* __restrict__ be,
               _Float16* __restrict__ outx)
{
    const int w = threadIdx.x >> 6, lane = threadIdx.x & 63;
    const int t = blockIdx.x * 4 + w, b = blockIdx.y;
    const size_t base = ((size_t)b * T_LEN + t) * C_CH + lane * 8;
    h8 xv = *reinterpret_cast<const h8*>(&x[base]);
    h8 yv = *reinterpret_cast<const h8*>(&y[base]);
    float v[8];
#pragma unroll
    for (int i = 0; i < 8; ++i) v[i] = (float)xv[i] + (float)yv[i];
    float s = 0.f, s2 = 0.f;
#pragma unroll
    for (int i = 0; i < 8; ++i) { s += v[i]; s2 += v[i] * v[i]; }
#pragma unroll
    for (int off = 1; off < 64; off <<= 1) {
        s  += __shfl_xor(s, off);
        s2 += __shfl_xor(s2, off);
    }
    const float mean = s * (1.f / C_CH);
    const float var  = s2 * (1.f / C_CH) - mean * mean;
    const float rstd = rsqrtf(var + 1e-5f);
    float4 g0 = *reinterpret_cast<const float4*>(&g[lane * 8]);
    float4 g1 = *reinterpret_cast<const float4*>(&g[lane * 8 + 4]);
    float4 b0 = *reinterpret_cast<const float4*>(&be[lane * 8]);
    float4 b1 = *reinterpret_cast<const float4*>(&be[lane * 8 + 4]);
    const float gg[8] = {g0.x, g0.y, g0.z, g0.w, g1.x, g1.y, g1.z, g1.w};
    const float bb[8] = {b0.x, b0.y, b0.z, b0.w, b1.x, b1.y, b1.z, b1.w};
    h8 ov;
#pragma unroll
    for (int i = 0; i < 8; ++i)
        ov[i] = (_Float16)((v[i] - mean) * rstd * gg[i] + bb[i]);
    *reinterpret_cast<h8*>(&outx[base]) = ov;
}

// out[b,t] = ( mask * sum_c pw[c]*x[b,t,c] + pb ) * mask   (one wave per t)
__global__ __launch_bounds__(256)
void proj_kernel(const _Float16* __restrict__ x, const float* __restrict__ pw,
                 const float* __restrict__ pb, const float* __restrict__ mask,
                 float* __restrict__ out)
{
    const int w = threadIdx.x >> 6, lane = threadIdx.x & 63;
    const int t = blockIdx.x * 4 + w, b = blockIdx.y;
    const size_t base = ((size_t)b * T_LEN + t) * C_CH + lane * 8;
    h8 xv = *reinterpret_cast<const h8*>(&x[base]);
    float4 p0 = *reinterpret_cast<const float4*>(&pw[lane * 8]);
    float4 p1 = *reinterpret_cast<const float4*>(&pw[lane * 8 + 4]);
    const float pp[8] = {p0.x, p0.y, p0.z, p0.w, p1.x, p1.y, p1.z, p1.w};
    float s = 0.f;
#pragma unroll
    for (int i = 0; i < 8; ++i) s += (float)xv[i] * pp[i];
#pragma unroll
    for (int off = 1; off < 64; off <<= 1) s += __shfl_xor(s, off);
    if (lane == 0) {
        const float mv = mask[(size_t)b * T_LEN + t];
        out[(size_t)b * T_LEN + t] = (s * mv + pb[0]) * mv;
    }
}

extern "C" void kernel_launch(void* const* d_in, const int* in_sizes, int n_in,
                              void* d_out, int out_size, void* d_ws, size_t ws_size,
                              hipStream_t stream)
{
    const float* x    = (const float*)d_in[0];
    const float* nf0  = (const float*)d_in[1];
    const float* xm   = (const float*)d_in[2];
    const float* spk  = (const float*)d_in[3];
    const float* prw  = (const float*)d_in[4];
    const float* prb  = (const float*)d_in[5];
    const float* f0w  = (const float*)d_in[6];
    const float* f0b  = (const float*)d_in[7];
    const float* cw   = (const float*)d_in[8];
    const float* cb   = (const float*)d_in[9];
    const float* pjw  = (const float*)d_in[10];
    const float* pjb  = (const float*)d_in[11];
    const float* qw   = (const float*)d_in[12];
    const float* qb   = (const float*)d_in[13];
    const float* kw   = (const float*)d_in[14];
    const float* kb   = (const float*)d_in[15];
    const float* vw   = (const float*)d_in[16];
    const float* vb   = (const float*)d_in[17];
    const float* ow   = (const float*)d_in[18];
    const float* ob   = (const float*)d_in[19];
    const float* ln0g = (const float*)d_in[20];
    const float* ln0b = (const float*)d_in[21];
    const float* ln1g = (const float*)d_in[22];
    const float* ln1b = (const float*)d_in[23];
    const float* f1w  = (const float*)d_in[24];
    const float* f1b  = (const float*)d_in[25];
    const float* f2w  = (const float*)d_in[26];
    const float* f2b  = (const float*)d_in[27];
    float* out = (float*)d_out;

    const size_t NCT = (size_t)B_SZ * C_CH * T_LEN;
    char* wp = (char*)d_ws;
    _Float16* xbuf = (_Float16*)wp; wp += NCT * 2;            // [b][t][512] residual
    _Float16* t0h  = (_Float16*)wp; wp += NCT * 2;            // [b][t][512] sublayer out
    _Float16* qk   = (_Float16*)wp; wp += NCT * 4;            // [b][t][1024]
    _Float16* vt   = (_Float16*)wp; wp += NCT * 2;            // [b][h*64+d][t]
    _Float16* obf  = (_Float16*)wp; wp += NCT * 2;            // [b][t][512]
    _Float16* h1   = (_Float16*)wp; wp += NCT * 8;            // [b][t][2048]
    _Float16* xT   = h1;                                       // alias (dead before h1 use)
    _Float16* spkT = obf;                                      // alias (dead before obf use)
    _Float16* Wqkv = (_Float16*)wp; wp += (size_t)L_N * 1536 * 512 * 2;
    _Float16* Wo   = (_Float16*)wp; wp += (size_t)L_N * 512 * 512 * 2;
    _Float16* Wcnd = (_Float16*)wp; wp += (size_t)512 * 256 * 2;
    _Float16* Wpre = (_Float16*)wp; wp += (size_t)512 * 512 * 3 * 2;
    _Float16* Wf1  = (_Float16*)wp; wp += (size_t)L_N * 2048 * 512 * 3 * 2;
    _Float16* Wf2  = (_Float16*)wp; wp += (size_t)L_N * 512 * 2048 * 3 * 2;
    float*    Bqkv = (float*)wp;    wp += (size_t)L_N * 1536 * 4;

    dim3 blk(256);
    dim3 gC(16, 4, B_SZ);       // M=512 convs
    dim3 gQKV(16, 12, B_SZ);    // M=1536 fused QKV
    dim3 gF(16, 16, B_SZ);      // M=2048 ffn1
    dim3 gAT(16, H_N, B_SZ);    // flash
    dim3 gLN(T_LEN / 4, B_SZ);

    // ---- weight prepack ----
    {
        int n;
        n = C_CH * S_CH;            cast_f16<<<(n + 255) / 256, blk, 0, stream>>>(cw, Wcnd, n);
        n = L_N * C_CH * C_CH;      cast_f16<<<(n + 255) / 256, blk, 0, stream>>>(ow, Wo, n);
        n = C_CH * C_CH * 3;        prepack_k3<<<(n + 255) / 256, blk, 0, stream>>>(prw, Wpre, C_CH, n);
        n = L_N * FC_CH * C_CH * 3; prepack_k3<<<(n + 255) / 256, blk, 0, stream>>>(f1w, Wf1, C_CH, n);
        n = L_N * C_CH * FC_CH * 3; prepack_k3<<<(n + 255) / 256, blk, 0, stream>>>(f2w, Wf2, FC_CH, n);
        n = L_N * 1536 * 512;       prepack_qkv<<<(n + 255) / 256, blk, 0, stream>>>(qw, kw, vw, qb, kb, vb, Wqkv, Bqkv);
    }

    // ---- prologue ----
    transpose_f0<<<dim3(64, 16, B_SZ), blk, 0, stream>>>(x, xT, C_CH, nf0, f0w, f0b, 1);
    transpose_f0<<<dim3(64, 8, B_SZ), blk, 0, stream>>>(spk, spkT, S_CH, nullptr, nullptr, nullptr, 0);
    conv_gemm_mfma<1, 1><<<gC, blk, 0, stream>>>(spkT, Wcnd, cb, xT, xm, t0h, nullptr, S_CH, C_CH, 0, 0, 0, 0);
    conv_gemm_mfma<3, 1><<<gC, blk, 0, stream>>>(t0h, Wpre, prb, nullptr, xm, xbuf, nullptr, C_CH, C_CH, 1, 0, 0, 1);

    for (int l = 0; l < L_N; ++l) {
        const size_t bo = (size_t)l * C_CH;
        conv_gemm_mfma<1, 3><<<gQKV, blk, 0, stream>>>(xbuf, Wqkv + (size_t)l * 1536 * 512, Bqkv + l * 1536,
                                                       nullptr, xm, qk, vt, C_CH, 1024, 0, 0, 0, 0);
        flash_attn_mfma<<<gAT, blk, 0, stream>>>(qk, vt, obf);
        conv_gemm_mfma<1, 1><<<gC, blk, 0, stream>>>(obf, Wo + (size_t)l * 512 * 512, ob + bo,
                                                     nullptr, xm, t0h, nullptr, C_CH, C_CH, 0, 0, 0, 0);
        ln_kernel<<<gLN, blk, 0, stream>>>(xbuf, t0h, ln0g + bo, ln0b + bo, xbuf);
        conv_gemm_mfma<3, 1><<<gF, blk, 0, stream>>>(xbuf, Wf1 + (size_t)l * FC_CH * C_CH * 3, f1b + (size_t)l * FC_CH,
                                                     nullptr, xm, h1, nullptr, C_CH, FC_CH, 2, 1, 1, 0);
        conv_gemm_mfma<3, 1><<<gC, blk, 0, stream>>>(h1, Wf2 + (size_t)l * C_CH * FC_CH * 3, f2b + bo,
                                                     nullptr, xm, t0h, nullptr, FC_CH, C_CH, 2, 0, 1, 1);
        ln_kernel<<<gLN, blk, 0, stream>>>(xbuf, t0h, ln1g + bo, ln1b + bo, xbuf);
    }
    proj_kernel<<<gLN, blk, 0, stream>>>(xbuf, pjw, pjb, xm, out);
}